// Round 17
// baseline (160.059 us; speedup 1.0000x reference)
//
#include <hip/hip_runtime.h>
#include <hip/hip_bf16.h>

typedef unsigned short ushortT;
typedef __attribute__((ext_vector_type(8))) short bf16x8;
typedef __attribute__((ext_vector_type(4))) float f32x4;
typedef __fp16 half2v __attribute__((ext_vector_type(2)));

// workspace float offsets
#define WS_XC   0          // 9216*256 fp32
#define WS_QB   2359296    // 9216*256 bf16
#define WS_POS  3538944    // 16*36*3
#define WS_K    3540736    // 72*256
#define WS_V    3559168    // 72*256
#define WS_WC   3577600    // 256*256 fp32
#define WS_B512 3675904    // 512
#define WS_DTAB 3676416    // 576*56 fp32 log-CPB displacement tables
#define WS_BIAS 3709184    // 16*36*4608 fp32 attn bias table

__device__ __forceinline__ float bf2f(ushortT u) {
  union { unsigned int i; float f; } c; c.i = ((unsigned int)u) << 16; return c.f;
}
__device__ __forceinline__ ushortT f2bf(float f) {
  union { float f; unsigned int i; } c; c.f = f;
  unsigned int lsb = (c.i >> 16) & 1;
  return (ushortT)((c.i + 0x7fff + lsb) >> 16);
}
__device__ __forceinline__ float ldg_f(const void* p, int i, int bf) {
  return bf ? bf2f(((const ushortT*)p)[i]) : ((const float*)p)[i];
}
// uniform dtype sniff of x's first 32 ushorts (fp32 -> wild bf16-exponents in even halves)
__device__ __forceinline__ int detect_bf(const void* x) {
  const ushortT* u = (const ushortT*)x;
  int wild = 0;
#pragma unroll
  for (int i = 0; i < 32; i++) {
    int e = (u[i] >> 7) & 0xFF;
    wild += (e != 0 && (e < 90 || e > 160)) ? 1 : 0;
  }
  return wild <= 4;   // 1 => bf16 inputs
}
__device__ __forceinline__ float logmap(float d) {
  return copysignf(__log2f(fabsf(d) + 1.f) * (1.f / 3.f), d);
}

// -------- k_wc: Wc = Wq*Win (fp32), bias512 = [b_in | Wq*b_in + b_q] --------
__global__ __launch_bounds__(256) void k_wc(const void* x, const void* w_in, const void* b_in,
                                            const void* w_q, const void* b_q,
                                            float* wc, float* bias512) {
  int o = blockIdx.x, tid = threadIdx.x;
  int bf = detect_bf(x);
  __shared__ float wq_s[256];
  __shared__ float red[256];
  wq_s[tid] = ldg_f(w_q, o * 256 + tid, bf);
  __syncthreads();
  float s = 0.f;
#pragma unroll 8
  for (int j = 0; j < 256; j++) s += wq_s[j] * ldg_f(w_in, j * 256 + tid, bf);
  wc[o * 256 + tid] = s;
  red[tid] = wq_s[tid] * ldg_f(b_in, tid, bf);
  __syncthreads();
  for (int m = 128; m; m >>= 1) {
    if (tid < m) red[tid] += red[tid + m];
    __syncthreads();
  }
  if (tid == 0) bias512[256 + o] = red[0] + ldg_f(b_q, o, bf);
  if (o == 0) bias512[tid] = ldg_f(b_in, tid, bf);
}

// -------- fused split-precision MFMA GEMM, double-buffered, truncation split --------
__global__ __launch_bounds__(256) void k_gemm_mfma(const void* x, const void* w_in, const float* wc,
                                                   const float* bias512, float* xc, ushortT* qb) {
  const int bf = detect_bf(x);
  __shared__ ushortT Ah[2][64 * 40], Al[2][64 * 40];
  __shared__ ushortT Bh[2][64 * 40], Bl[2][64 * 40];
  int tid = threadIdx.x;
  int bid = blockIdx.x;
  int colT = bid / 144, rowT = bid % 144;
  int col0 = colT * 64;
  int row0 = rowT * 64;
  int bt = row0 / 576;
  int hw0 = row0 % 576;
  const int isW = (col0 < 256);
  const ushortT* xB = (const ushortT*)x;
  const float*   xF = (const float*)x;
  const ushortT* wB = (const ushortT*)w_in;
  const float*   wF = (const float*)w_in;
  int ar = tid & 63, aoct = tid >> 6;
  int bn = tid >> 2, bko = tid & 3;
  int w = tid >> 6, l = tid & 63;
  int wr = w >> 1, wcq = w & 1;
  int lr = l & 15, lk = l >> 4;
  f32x4 acc[2][2] = {};

  float va[8], vb[8];
  auto loadA = [&](int kt) {
    int kbase = (bt * 256 + kt * 32 + aoct * 8) * 576 + hw0 + ar;
#pragma unroll
    for (int j = 0; j < 8; j++)
      va[j] = bf ? bf2f(xB[kbase + j * 576]) : xF[kbase + j * 576];
  };
  auto loadB = [&](int kt) {
    if (isW) {
      if (bf) {
        const ushortT* pp = wB + (col0 + bn) * 256 + kt * 32 + bko * 8;
#pragma unroll
        for (int j = 0; j < 8; j++) vb[j] = bf2f(pp[j]);
      } else {
        const float* pp = wF + (col0 + bn) * 256 + kt * 32 + bko * 8;
        float4 f0 = *(const float4*)pp;
        float4 f1 = *(const float4*)(pp + 4);
        vb[0] = f0.x; vb[1] = f0.y; vb[2] = f0.z; vb[3] = f0.w;
        vb[4] = f1.x; vb[5] = f1.y; vb[6] = f1.z; vb[7] = f1.w;
      }
    } else {
      const float* pp = wc + (col0 - 256 + bn) * 256 + kt * 32 + bko * 8;
      float4 f0 = *(const float4*)pp;
      float4 f1 = *(const float4*)(pp + 4);
      vb[0] = f0.x; vb[1] = f0.y; vb[2] = f0.z; vb[3] = f0.w;
      vb[4] = f1.x; vb[5] = f1.y; vb[6] = f1.z; vb[7] = f1.w;
    }
  };
  auto writeAB = [&](int buf) {
    unsigned ua[8], ra[8];
#pragma unroll
    for (int j = 0; j < 8; j++) {
      ua[j] = __float_as_uint(va[j]);
      ra[j] = __float_as_uint(va[j] - __uint_as_float(ua[j] & 0xffff0000u));
    }
    int4 ph, pl;
    ph.x = (int)((ua[0] >> 16) | (ua[1] & 0xffff0000u));
    ph.y = (int)((ua[2] >> 16) | (ua[3] & 0xffff0000u));
    ph.z = (int)((ua[4] >> 16) | (ua[5] & 0xffff0000u));
    ph.w = (int)((ua[6] >> 16) | (ua[7] & 0xffff0000u));
    pl.x = (int)((ra[0] >> 16) | (ra[1] & 0xffff0000u));
    pl.y = (int)((ra[2] >> 16) | (ra[3] & 0xffff0000u));
    pl.z = (int)((ra[4] >> 16) | (ra[5] & 0xffff0000u));
    pl.w = (int)((ra[6] >> 16) | (ra[7] & 0xffff0000u));
    *(int4*)&Ah[buf][ar * 40 + aoct * 8] = ph;
    *(int4*)&Al[buf][ar * 40 + aoct * 8] = pl;
#pragma unroll
    for (int j = 0; j < 8; j++) {
      ua[j] = __float_as_uint(vb[j]);
      ra[j] = __float_as_uint(vb[j] - __uint_as_float(ua[j] & 0xffff0000u));
    }
    ph.x = (int)((ua[0] >> 16) | (ua[1] & 0xffff0000u));
    ph.y = (int)((ua[2] >> 16) | (ua[3] & 0xffff0000u));
    ph.z = (int)((ua[4] >> 16) | (ua[5] & 0xffff0000u));
    ph.w = (int)((ua[6] >> 16) | (ua[7] & 0xffff0000u));
    pl.x = (int)((ra[0] >> 16) | (ra[1] & 0xffff0000u));
    pl.y = (int)((ra[2] >> 16) | (ra[3] & 0xffff0000u));
    pl.z = (int)((ra[4] >> 16) | (ra[5] & 0xffff0000u));
    pl.w = (int)((ra[6] >> 16) | (ra[7] & 0xffff0000u));
    *(int4*)&Bh[buf][bn * 40 + bko * 8] = ph;
    *(int4*)&Bl[buf][bn * 40 + bko * 8] = pl;
  };

  loadA(0); loadB(0);
  writeAB(0);
  __syncthreads();
  for (int kt = 0; kt < 8; kt++) {
    int cur = kt & 1;
    if (kt < 7) { loadA(kt + 1); loadB(kt + 1); }
    bf16x8 a0h = *(const bf16x8*)&Ah[cur][(wr * 32 + 0 * 16 + lr) * 40 + lk * 8];
    bf16x8 a1h = *(const bf16x8*)&Ah[cur][(wr * 32 + 1 * 16 + lr) * 40 + lk * 8];
    bf16x8 a0l = *(const bf16x8*)&Al[cur][(wr * 32 + 0 * 16 + lr) * 40 + lk * 8];
    bf16x8 a1l = *(const bf16x8*)&Al[cur][(wr * 32 + 1 * 16 + lr) * 40 + lk * 8];
    bf16x8 b0h = *(const bf16x8*)&Bh[cur][(wcq * 32 + 0 * 16 + lr) * 40 + lk * 8];
    bf16x8 b1h = *(const bf16x8*)&Bh[cur][(wcq * 32 + 1 * 16 + lr) * 40 + lk * 8];
    bf16x8 b0l = *(const bf16x8*)&Bl[cur][(wcq * 32 + 0 * 16 + lr) * 40 + lk * 8];
    bf16x8 b1l = *(const bf16x8*)&Bl[cur][(wcq * 32 + 1 * 16 + lr) * 40 + lk * 8];
    acc[0][0] = __builtin_amdgcn_mfma_f32_16x16x32_bf16(a0h, b0h, acc[0][0], 0, 0, 0);
    acc[0][0] = __builtin_amdgcn_mfma_f32_16x16x32_bf16(a0h, b0l, acc[0][0], 0, 0, 0);
    acc[0][0] = __builtin_amdgcn_mfma_f32_16x16x32_bf16(a0l, b0h, acc[0][0], 0, 0, 0);
    acc[0][1] = __builtin_amdgcn_mfma_f32_16x16x32_bf16(a0h, b1h, acc[0][1], 0, 0, 0);
    acc[0][1] = __builtin_amdgcn_mfma_f32_16x16x32_bf16(a0h, b1l, acc[0][1], 0, 0, 0);
    acc[0][1] = __builtin_amdgcn_mfma_f32_16x16x32_bf16(a0l, b1h, acc[0][1], 0, 0, 0);
    acc[1][0] = __builtin_amdgcn_mfma_f32_16x16x32_bf16(a1h, b0h, acc[1][0], 0, 0, 0);
    acc[1][0] = __builtin_amdgcn_mfma_f32_16x16x32_bf16(a1h, b0l, acc[1][0], 0, 0, 0);
    acc[1][0] = __builtin_amdgcn_mfma_f32_16x16x32_bf16(a1l, b0h, acc[1][0], 0, 0, 0);
    acc[1][1] = __builtin_amdgcn_mfma_f32_16x16x32_bf16(a1h, b1h, acc[1][1], 0, 0, 0);
    acc[1][1] = __builtin_amdgcn_mfma_f32_16x16x32_bf16(a1h, b1l, acc[1][1], 0, 0, 0);
    acc[1][1] = __builtin_amdgcn_mfma_f32_16x16x32_bf16(a1l, b1h, acc[1][1], 0, 0, 0);
    if (kt < 7) writeAB(cur ^ 1);
    __syncthreads();
  }
#pragma unroll
  for (int m = 0; m < 2; m++) {
#pragma unroll
    for (int n = 0; n < 2; n++) {
#pragma unroll
      for (int i = 0; i < 4; i++) {
        int row = row0 + wr * 32 + m * 16 + lk * 4 + i;
        int col = col0 + wcq * 32 + n * 16 + lr;
        float v = acc[m][n][i] + bias512[col];
        if (isW) xc[row * 256 + col] = v;
        else     qb[row * 256 + (col - 256)] = f2bf(v);
      }
    }
  }
}

// ---- offsets: tap-parallel dw-conv + LN + GELU + proj + ref + clip + dtab epilogue ----
__global__ __launch_bounds__(256) void k_offsets(const void* x, const ushortT* qb, const void* w_dw,
                                                 const void* b_dw, const void* ln_g, const void* ln_b,
                                                 const void* w_proj, float* pos, float* dtab) {
  __shared__ float wdw[243 * 33];   // [tap][ch], stride 33
  __shared__ float part[8][33];
  __shared__ float ptile[3];
  int bid = blockIdx.x;             // g*36 + nn
  int g = bid / 36, nn = bid % 36;
  int b = g >> 3, nh = g & 7;
  int tk = nn / 9, hk = (nn / 3) % 3, wk = nn % 3;
  int tid = threadIdx.x;
  int ch = tid & 31, grp = tid >> 5;
  int bf = detect_bf(x);
  for (int i = tid; i < 7776; i += 256) {
    int c = i / 243, tap = i % 243;
    wdw[tap * 33 + c] = ldg_f(w_dw, i, bf);
  }
  __syncthreads();
  float sum = 0.f;
  for (int tap = grp; tap < 243; tap += 8) {
    int dt = tap / 81, rem = tap % 81, dh = rem / 9, dw = rem % 9;
    int t = tk * 2 - 1 + dt, h = hk * 8 - 4 + dh, w = wk * 8 - 4 + dw;
    if (t < 0 || t >= 8 || h < 0 || h >= 24 || w < 0 || w >= 24) continue;
    float qv = bf2f(qb[((b * 8 + t) * 576 + h * 24 + w) * 256 + nh * 32 + ch]);
    sum += qv * wdw[tap * 33 + ch];
  }
  part[grp][ch] = sum;
  __syncthreads();
  if (tid < 32) {
    float v = ldg_f(b_dw, ch, bf);
#pragma unroll
    for (int j = 0; j < 8; j++) v += part[j][ch];
    float s1 = v;
    for (int m = 16; m; m >>= 1) s1 += __shfl_xor(s1, m);
    float mu = s1 * (1.f / 32.f);
    float d = v - mu;
    float s2 = d * d;
    for (int m = 16; m; m >>= 1) s2 += __shfl_xor(s2, m);
    float o = d * rsqrtf(s2 * (1.f / 32.f) + 1e-5f) * ldg_f(ln_g, ch, bf) + ldg_f(ln_b, ch, bf);
    o = 0.5f * o * (1.f + erff(o * 0.70710678118654752f));
    float res[3];
#pragma unroll
    for (int p = 0; p < 3; p++) {
      float t3 = o * ldg_f(w_proj, p * 32 + ch, bf);
      for (int m = 16; m; m >>= 1) t3 += __shfl_xor(t3, m);
      res[p] = t3;
    }
    if (ch == 0) {
      float ref0 = ((tk + 0.5f) / 3.f) * 2.f - 1.f;
      float ref1 = ((hk + 0.5f) / 2.f) * 2.f - 1.f;
      float ref2 = ((wk + 0.5f) / 2.f) * 2.f - 1.f;
      float p0 = fminf(1.f, fmaxf(-1.f, res[0] + ref0));
      float p1 = fminf(1.f, fmaxf(-1.f, res[1] + ref1));
      float p2 = fminf(1.f, fmaxf(-1.f, res[2] + ref2));
      pos[bid * 3 + 0] = p0;
      pos[bid * 3 + 1] = p1;
      pos[bid * 3 + 2] = p2;
      ptile[0] = p0; ptile[1] = p1; ptile[2] = p2;
    }
  }
  __syncthreads();
  // log-CPB displacement tables: [0..7]=d0(t), [8..31]=d1(hh), [32..55]=d2(ww)
  if (tid < 56) {
    float dv;
    if (tid < 8)       dv = ((float)tid        * (2.f / 7.f)  - 1.f - ptile[0]) * 4.f;
    else if (tid < 32) dv = ((float)(tid - 8)  * (2.f / 23.f) - 1.f - ptile[1]) * 4.f;
    else               dv = ((float)(tid - 32) * (2.f / 23.f) - 1.f - ptile[2]) * 4.f;
    dtab[bid * 56 + tid] = logmap(dv);
  }
}

// ---- bias table: grid (t=8, bid=576); fp16-packed MLP, a0 hoisted per block ----
__global__ __launch_bounds__(256) void k_biastab(const void* x, const void* rpe_w1,
                                                 const void* rpe_b1, const void* rpe_w2,
                                                 const float* dtab, float* biastab) {
  int t = blockIdx.x, bid = blockIdx.y;
  int tid = threadIdx.x;
  int bf = detect_bf(x);
  __shared__ float dts[56];
  if (tid < 56) dts[tid] = dtab[bid * 56 + tid];
  __syncthreads();
  half2v wyp[16], wzp[16], w2p[16], a0[16];
  {
    float d0 = dts[t];
    half2v d0h = __builtin_amdgcn_cvt_pkrtz(d0, d0);
#pragma unroll
    for (int j = 0; j < 16; j++) {
      half2v wxp = __builtin_amdgcn_cvt_pkrtz(ldg_f(rpe_w1, (2*j)*3+0, bf), ldg_f(rpe_w1, (2*j+1)*3+0, bf));
      half2v wbp = __builtin_amdgcn_cvt_pkrtz(ldg_f(rpe_b1, 2*j, bf), ldg_f(rpe_b1, 2*j+1, bf));
      wyp[j] = __builtin_amdgcn_cvt_pkrtz(ldg_f(rpe_w1, (2*j)*3+1, bf), ldg_f(rpe_w1, (2*j+1)*3+1, bf));
      wzp[j] = __builtin_amdgcn_cvt_pkrtz(ldg_f(rpe_w1, (2*j)*3+2, bf), ldg_f(rpe_w1, (2*j+1)*3+2, bf));
      w2p[j] = __builtin_amdgcn_cvt_pkrtz(ldg_f(rpe_w2, 2*j, bf), ldg_f(rpe_w2, 2*j+1, bf));
      a0[j] = d0h * wxp + wbp;
    }
  }
  half2v zero = __builtin_amdgcn_cvt_pkrtz(0.f, 0.f);
  float* brow = biastab + bid * 4608 + t * 576;
  for (int hw = tid; hw < 576; hw += 256) {
    int hh = hw / 24, ww = hw % 24;
    float d1 = dts[8 + hh], d2 = dts[32 + ww];
    half2v d1h = __builtin_amdgcn_cvt_pkrtz(d1, d1);
    half2v d2h = __builtin_amdgcn_cvt_pkrtz(d2, d2);
    float s = 0.f;
#pragma unroll
    for (int j = 0; j < 16; j++) {
      half2v hb = d1h * wyp[j] + (d2h * wzp[j] + a0[j]);
      half2v r;
      asm("v_pk_max_f16 %0, %1, %2" : "=v"(r) : "v"(hb), "v"(zero));
      asm("v_dot2_f32_f16 %0, %1, %2, %0" : "+v"(s) : "v"(r), "v"(w2p[j]));
    }
    brow[hw] = s;
  }
}

// ---- fused trilinear sample + k/v 1x1 conv: 288 blocks, pair-split dot ----
__global__ __launch_bounds__(256) void k_svkv(const void* x, const float* xc_rm, const float* pos,
                                              const void* w_k, const void* b_k,
                                              const void* w_v, const void* b_v,
                                              float* k_rm, float* v_rm) {
  int bx = blockIdx.x;
  int row = bx >> 2, quad = bx & 3;
  int sel = quad >> 1, colhalf = quad & 1;
  int b = row / 36, nn = row % 36;
  int tid = threadIdx.x;
  int bf = detect_bf(x);
  __shared__ float a[256];
  {
    int nh = tid >> 5;
    int g = b * 8 + nh;
    float p0 = pos[(g * 36 + nn) * 3 + 0];
    float p1 = pos[(g * 36 + nn) * 3 + 1];
    float p2 = pos[(g * 36 + nn) * 3 + 2];
    float ix = (p0 + 1.f) * 0.5f * 23.f;
    float iy = (p2 + 1.f) * 0.5f * 23.f;
    float iz = (p1 + 1.f) * 0.5f * 7.f;
    float x0f = floorf(ix), y0f = floorf(iy), z0f = floorf(iz);
    float fx = ix - x0f, fy = iy - y0f, fz = iz - z0f;
    int x0 = min(max((int)x0f, 0), 23), x1 = min(x0 + 1, 23);
    int y0 = min(max((int)y0f, 0), 23), y1 = min(y0 + 1, 23);
    int z0 = min(max((int)z0f, 0), 7),  z1 = min(z0 + 1, 7);
#define AT(z, y, x) xc_rm[(((b * 8 + (z)) * 576 + (y) * 24 + (x)) * 256 + tid)]
    a[tid] =
      AT(z0, y0, x0) * (1.f - fz) * (1.f - fy) * (1.f - fx) + AT(z0, y0, x1) * (1.f - fz) * (1.f - fy) * fx +
      AT(z0, y1, x0) * (1.f - fz) * fy * (1.f - fx)         + AT(z0, y1, x1) * (1.f - fz) * fy * fx +
      AT(z1, y0, x0) * fz * (1.f - fy) * (1.f - fx)         + AT(z1, y0, x1) * fz * (1.f - fy) * fx +
      AT(z1, y1, x0) * fz * fy * (1.f - fx)                 + AT(z1, y1, x1) * fz * fy * fx;
#undef AT
  }
  __syncthreads();
  const void* w = sel ? w_v : w_k;
  const void* bb = sel ? b_v : b_k;
  int col = colhalf * 128 + (tid >> 1);
  int half = tid & 1;
  int c0 = half * 128;
  float s = 0.f;
  if (bf) {
    const ushortT* wp = (const ushortT*)w + col * 256 + c0;
#pragma unroll 4
    for (int c = 0; c < 128; c += 8) {
      ushort4 k0 = *(const ushort4*)(wp + c), k1 = *(const ushort4*)(wp + c + 4);
      s += a[c0+c+0]*bf2f(k0.x) + a[c0+c+1]*bf2f(k0.y) + a[c0+c+2]*bf2f(k0.z) + a[c0+c+3]*bf2f(k0.w)
         + a[c0+c+4]*bf2f(k1.x) + a[c0+c+5]*bf2f(k1.y) + a[c0+c+6]*bf2f(k1.z) + a[c0+c+7]*bf2f(k1.w);
    }
  } else {
    const float* wp = (const float*)w + col * 256 + c0;
#pragma unroll 8
    for (int c = 0; c < 128; c += 4) {
      float4 k4 = *(const float4*)(wp + c);
      s += a[c0+c]*k4.x + a[c0+c+1]*k4.y + a[c0+c+2]*k4.z + a[c0+c+3]*k4.w;
    }
  }
  s += __shfl_xor(s, 1);
  if (half == 0) {
    float* outp = sel ? v_rm : k_rm;
    outp[row * 256 + col] = s + ldg_f(bb, col, bf);
  }
}

// ---- attention: QK (bf16 LDS) + bias-table add + softmax + PV; 8-way sub split ----
__global__ __launch_bounds__(256) void k_attn(const void* x, const ushortT* qb,
                                              const float* k_rm, const float* v_rm,
                                              const float* biastab, void* outp) {
  __shared__ ushortT ksb[36][32];
  __shared__ ushortT vsb[36][32];
  int g = blockIdx.y, b = g >> 3, nh = g & 7;
  int tid = threadIdx.x;
  int bf = detect_bf(x);
  for (int e = tid; e < 36 * 32; e += 256) {
    int nn = e >> 5, ch = e & 31;
    ksb[nn][ch] = f2bf(k_rm[(b * 36 + nn) * 256 + nh * 32 + ch]);
    vsb[nn][ch] = f2bf(v_rm[(b * 36 + nn) * 256 + nh * 32 + ch]);
  }
  __syncthreads();

  int sub = tid & 7, chb = sub * 4;
  int mm = blockIdx.x * 32 + (tid >> 3);
  int t = mm / 576, hw = mm % 576;
  float qreg[4];
  {
    ushort4 u = *(const ushort4*)&qb[(b * 4608 + mm) * 256 + nh * 32 + chb];
    qreg[0] = bf2f(u.x); qreg[1] = bf2f(u.y); qreg[2] = bf2f(u.z); qreg[3] = bf2f(u.w);
  }
  const float scale = 0.17677669529663687f;
  const float* brow = biastab + g * 36 * 4608 + mm;
  float p[36];
#pragma unroll
  for (int nn = 0; nn < 36; nn++) {
    ushort4 k4 = *(const ushort4*)&ksb[nn][chb];
    float s = qreg[0] * bf2f(k4.x) + qreg[1] * bf2f(k4.y)
            + qreg[2] * bf2f(k4.z) + qreg[3] * bf2f(k4.w);
    p[nn] = s * scale;
  }
#pragma unroll
  for (int nn = 0; nn < 36; nn++) {
    p[nn] += __shfl_xor(p[nn], 1);
    p[nn] += __shfl_xor(p[nn], 2);
    p[nn] += __shfl_xor(p[nn], 4);
    p[nn] += brow[nn * 4608];
  }
  float mx = -1e30f;
#pragma unroll
  for (int nn = 0; nn < 36; nn++) mx = fmaxf(mx, p[nn]);
  float se = 0.f;
#pragma unroll
  for (int nn = 0; nn < 36; nn++) {
    float e = __expf(p[nn] - mx);
    p[nn] = e;
    se += e;
  }
  float inv = 1.f / se;
  float acc[4] = {};
#pragma unroll
  for (int nn = 0; nn < 36; nn++) {
    float pr = p[nn] * inv;
    ushort4 v4 = *(const ushort4*)&vsb[nn][chb];
    acc[0] += pr * bf2f(v4.x); acc[1] += pr * bf2f(v4.y);
    acc[2] += pr * bf2f(v4.z); acc[3] += pr * bf2f(v4.w);
  }
  int obase = ((b * 8 + t) * 256 + nh * 32 + chb) * 576 + hw;
  if (bf) {
    __hip_bfloat16* o = (__hip_bfloat16*)outp;
#pragma unroll
    for (int j = 0; j < 4; j++) o[obase + j * 576] = __float2bfloat16(acc[j]);
  } else {
    float* o = (float*)outp;
#pragma unroll
    for (int j = 0; j < 4; j++) o[obase + j * 576] = acc[j];
  }
}

extern "C" void kernel_launch(void* const* d_in, const int* in_sizes, int n_in,
                              void* d_out, int out_size, void* d_ws, size_t ws_size,
                              hipStream_t stream) {
  const void* x        = d_in[0];
  const void* w_in     = d_in[1];
  const void* b_in     = d_in[2];
  const void* w_q      = d_in[3];
  const void* b_q      = d_in[4];
  const void* w_off_dw = d_in[5];
  const void* b_off_dw = d_in[6];
  const void* ln_g     = d_in[7];
  const void* ln_b     = d_in[8];
  const void* w_off_pj = d_in[9];
  const void* w_k      = d_in[10];
  const void* b_k      = d_in[11];
  const void* w_v      = d_in[12];
  const void* b_v      = d_in[13];
  const void* rpe_w1   = d_in[14];
  const void* rpe_b1   = d_in[15];
  const void* rpe_w2   = d_in[16];

  float* ws      = (float*)d_ws;
  float* xc      = ws + WS_XC;
  ushortT* qb    = (ushortT*)(ws + WS_QB);
  float* pos     = ws + WS_POS;
  float* krm     = ws + WS_K;
  float* vrm     = ws + WS_V;
  float* wcf     = ws + WS_WC;
  float* b512    = ws + WS_B512;
  float* dtab    = ws + WS_DTAB;
  float* biastab = ws + WS_BIAS;

  k_wc<<<256, 256, 0, stream>>>(x, w_in, b_in, w_q, b_q, wcf, b512);
  k_gemm_mfma<<<1152, 256, 0, stream>>>(x, w_in, wcf, b512, xc, qb);
  k_offsets<<<576, 256, 0, stream>>>(x, qb, w_off_dw, b_off_dw, ln_g, ln_b, w_off_pj, pos, dtab);
  k_biastab<<<dim3(8, 576), 256, 0, stream>>>(x, rpe_w1, rpe_b1, rpe_w2, dtab, biastab);
  k_svkv<<<288, 256, 0, stream>>>(x, xc, pos, w_k, b_k, w_v, b_v, krm, vrm);
  k_attn<<<dim3(144, 16), 256, 0, stream>>>(x, qb, krm, vrm, biastab, d_out);
}

// Round 18
// 139.854 us; speedup vs baseline: 1.1445x; 1.1445x over previous
//
#include <hip/hip_runtime.h>
#include <hip/hip_bf16.h>

typedef unsigned short ushortT;
typedef __attribute__((ext_vector_type(8))) short bf16x8;
typedef __attribute__((ext_vector_type(4))) float f32x4;

// workspace float offsets
#define WS_XC   0          // 9216*256 fp32
#define WS_QB   2359296    // 9216*256 bf16
#define WS_POS  3538944    // 16*36*3
#define WS_K    3540736    // 72*256
#define WS_V    3559168    // 72*256
#define WS_WC   3577600    // 256*256 fp32
#define WS_B512 3675904    // 512
#define WS_DTAB 3676416    // 576*56 fp32 log-CPB displacement tables
#define WS_BIAS 3709184    // 16*36*4608 fp32 attn bias table

__device__ __forceinline__ float bf2f(ushortT u) {
  union { unsigned int i; float f; } c; c.i = ((unsigned int)u) << 16; return c.f;
}
__device__ __forceinline__ ushortT f2bf(float f) {
  union { float f; unsigned int i; } c; c.f = f;
  unsigned int lsb = (c.i >> 16) & 1;
  return (ushortT)((c.i + 0x7fff + lsb) >> 16);
}
__device__ __forceinline__ float ldg_f(const void* p, int i, int bf) {
  return bf ? bf2f(((const ushortT*)p)[i]) : ((const float*)p)[i];
}
// uniform dtype sniff of x's first 32 ushorts (fp32 -> wild bf16-exponents in even halves)
__device__ __forceinline__ int detect_bf(const void* x) {
  const ushortT* u = (const ushortT*)x;
  int wild = 0;
#pragma unroll
  for (int i = 0; i < 32; i++) {
    int e = (u[i] >> 7) & 0xFF;
    wild += (e != 0 && (e < 90 || e > 160)) ? 1 : 0;
  }
  return wild <= 4;   // 1 => bf16 inputs
}
__device__ __forceinline__ float logmap(float d) {
  return copysignf(__log2f(fabsf(d) + 1.f) * (1.f / 3.f), d);
}

// -------- k_wc: Wc = Wq*Win (fp32), bias512 = [b_in | Wq*b_in + b_q] --------
__global__ __launch_bounds__(256) void k_wc(const void* x, const void* w_in, const void* b_in,
                                            const void* w_q, const void* b_q,
                                            float* wc, float* bias512) {
  int o = blockIdx.x, tid = threadIdx.x;
  int bf = detect_bf(x);
  __shared__ float wq_s[256];
  __shared__ float red[256];
  wq_s[tid] = ldg_f(w_q, o * 256 + tid, bf);
  __syncthreads();
  float s = 0.f;
#pragma unroll 8
  for (int j = 0; j < 256; j++) s += wq_s[j] * ldg_f(w_in, j * 256 + tid, bf);
  wc[o * 256 + tid] = s;
  red[tid] = wq_s[tid] * ldg_f(b_in, tid, bf);
  __syncthreads();
  for (int m = 128; m; m >>= 1) {
    if (tid < m) red[tid] += red[tid + m];
    __syncthreads();
  }
  if (tid == 0) bias512[256 + o] = red[0] + ldg_f(b_q, o, bf);
  if (o == 0) bias512[tid] = ldg_f(b_in, tid, bf);
}

// -------- fused split-precision MFMA GEMM, double-buffered, truncation split --------
__global__ __launch_bounds__(256) void k_gemm_mfma(const void* x, const void* w_in, const float* wc,
                                                   const float* bias512, float* xc, ushortT* qb) {
  const int bf = detect_bf(x);
  __shared__ ushortT Ah[2][64 * 40], Al[2][64 * 40];
  __shared__ ushortT Bh[2][64 * 40], Bl[2][64 * 40];
  int tid = threadIdx.x;
  int bid = blockIdx.x;
  int colT = bid / 144, rowT = bid % 144;
  int col0 = colT * 64;
  int row0 = rowT * 64;
  int bt = row0 / 576;
  int hw0 = row0 % 576;
  const int isW = (col0 < 256);
  const ushortT* xB = (const ushortT*)x;
  const float*   xF = (const float*)x;
  const ushortT* wB = (const ushortT*)w_in;
  const float*   wF = (const float*)w_in;
  int ar = tid & 63, aoct = tid >> 6;
  int bn = tid >> 2, bko = tid & 3;
  int w = tid >> 6, l = tid & 63;
  int wr = w >> 1, wcq = w & 1;
  int lr = l & 15, lk = l >> 4;
  f32x4 acc[2][2] = {};

  float va[8], vb[8];
  auto loadA = [&](int kt) {
    int kbase = (bt * 256 + kt * 32 + aoct * 8) * 576 + hw0 + ar;
#pragma unroll
    for (int j = 0; j < 8; j++)
      va[j] = bf ? bf2f(xB[kbase + j * 576]) : xF[kbase + j * 576];
  };
  auto loadB = [&](int kt) {
    if (isW) {
      if (bf) {
        const ushortT* pp = wB + (col0 + bn) * 256 + kt * 32 + bko * 8;
#pragma unroll
        for (int j = 0; j < 8; j++) vb[j] = bf2f(pp[j]);
      } else {
        const float* pp = wF + (col0 + bn) * 256 + kt * 32 + bko * 8;
        float4 f0 = *(const float4*)pp;
        float4 f1 = *(const float4*)(pp + 4);
        vb[0] = f0.x; vb[1] = f0.y; vb[2] = f0.z; vb[3] = f0.w;
        vb[4] = f1.x; vb[5] = f1.y; vb[6] = f1.z; vb[7] = f1.w;
      }
    } else {
      const float* pp = wc + (col0 - 256 + bn) * 256 + kt * 32 + bko * 8;
      float4 f0 = *(const float4*)pp;
      float4 f1 = *(const float4*)(pp + 4);
      vb[0] = f0.x; vb[1] = f0.y; vb[2] = f0.z; vb[3] = f0.w;
      vb[4] = f1.x; vb[5] = f1.y; vb[6] = f1.z; vb[7] = f1.w;
    }
  };
  auto writeAB = [&](int buf) {
    unsigned ua[8], ra[8];
#pragma unroll
    for (int j = 0; j < 8; j++) {
      ua[j] = __float_as_uint(va[j]);
      ra[j] = __float_as_uint(va[j] - __uint_as_float(ua[j] & 0xffff0000u));
    }
    int4 ph, pl;
    ph.x = (int)((ua[0] >> 16) | (ua[1] & 0xffff0000u));
    ph.y = (int)((ua[2] >> 16) | (ua[3] & 0xffff0000u));
    ph.z = (int)((ua[4] >> 16) | (ua[5] & 0xffff0000u));
    ph.w = (int)((ua[6] >> 16) | (ua[7] & 0xffff0000u));
    pl.x = (int)((ra[0] >> 16) | (ra[1] & 0xffff0000u));
    pl.y = (int)((ra[2] >> 16) | (ra[3] & 0xffff0000u));
    pl.z = (int)((ra[4] >> 16) | (ra[5] & 0xffff0000u));
    pl.w = (int)((ra[6] >> 16) | (ra[7] & 0xffff0000u));
    *(int4*)&Ah[buf][ar * 40 + aoct * 8] = ph;
    *(int4*)&Al[buf][ar * 40 + aoct * 8] = pl;
#pragma unroll
    for (int j = 0; j < 8; j++) {
      ua[j] = __float_as_uint(vb[j]);
      ra[j] = __float_as_uint(vb[j] - __uint_as_float(ua[j] & 0xffff0000u));
    }
    ph.x = (int)((ua[0] >> 16) | (ua[1] & 0xffff0000u));
    ph.y = (int)((ua[2] >> 16) | (ua[3] & 0xffff0000u));
    ph.z = (int)((ua[4] >> 16) | (ua[5] & 0xffff0000u));
    ph.w = (int)((ua[6] >> 16) | (ua[7] & 0xffff0000u));
    pl.x = (int)((ra[0] >> 16) | (ra[1] & 0xffff0000u));
    pl.y = (int)((ra[2] >> 16) | (ra[3] & 0xffff0000u));
    pl.z = (int)((ra[4] >> 16) | (ra[5] & 0xffff0000u));
    pl.w = (int)((ra[6] >> 16) | (ra[7] & 0xffff0000u));
    *(int4*)&Bh[buf][bn * 40 + bko * 8] = ph;
    *(int4*)&Bl[buf][bn * 40 + bko * 8] = pl;
  };

  loadA(0); loadB(0);
  writeAB(0);
  __syncthreads();
  for (int kt = 0; kt < 8; kt++) {
    int cur = kt & 1;
    if (kt < 7) { loadA(kt + 1); loadB(kt + 1); }
    bf16x8 a0h = *(const bf16x8*)&Ah[cur][(wr * 32 + 0 * 16 + lr) * 40 + lk * 8];
    bf16x8 a1h = *(const bf16x8*)&Ah[cur][(wr * 32 + 1 * 16 + lr) * 40 + lk * 8];
    bf16x8 a0l = *(const bf16x8*)&Al[cur][(wr * 32 + 0 * 16 + lr) * 40 + lk * 8];
    bf16x8 a1l = *(const bf16x8*)&Al[cur][(wr * 32 + 1 * 16 + lr) * 40 + lk * 8];
    bf16x8 b0h = *(const bf16x8*)&Bh[cur][(wcq * 32 + 0 * 16 + lr) * 40 + lk * 8];
    bf16x8 b1h = *(const bf16x8*)&Bh[cur][(wcq * 32 + 1 * 16 + lr) * 40 + lk * 8];
    bf16x8 b0l = *(const bf16x8*)&Bl[cur][(wcq * 32 + 0 * 16 + lr) * 40 + lk * 8];
    bf16x8 b1l = *(const bf16x8*)&Bl[cur][(wcq * 32 + 1 * 16 + lr) * 40 + lk * 8];
    acc[0][0] = __builtin_amdgcn_mfma_f32_16x16x32_bf16(a0h, b0h, acc[0][0], 0, 0, 0);
    acc[0][0] = __builtin_amdgcn_mfma_f32_16x16x32_bf16(a0h, b0l, acc[0][0], 0, 0, 0);
    acc[0][0] = __builtin_amdgcn_mfma_f32_16x16x32_bf16(a0l, b0h, acc[0][0], 0, 0, 0);
    acc[0][1] = __builtin_amdgcn_mfma_f32_16x16x32_bf16(a0h, b1h, acc[0][1], 0, 0, 0);
    acc[0][1] = __builtin_amdgcn_mfma_f32_16x16x32_bf16(a0h, b1l, acc[0][1], 0, 0, 0);
    acc[0][1] = __builtin_amdgcn_mfma_f32_16x16x32_bf16(a0l, b1h, acc[0][1], 0, 0, 0);
    acc[1][0] = __builtin_amdgcn_mfma_f32_16x16x32_bf16(a1h, b0h, acc[1][0], 0, 0, 0);
    acc[1][0] = __builtin_amdgcn_mfma_f32_16x16x32_bf16(a1h, b0l, acc[1][0], 0, 0, 0);
    acc[1][0] = __builtin_amdgcn_mfma_f32_16x16x32_bf16(a1l, b0h, acc[1][0], 0, 0, 0);
    acc[1][1] = __builtin_amdgcn_mfma_f32_16x16x32_bf16(a1h, b1h, acc[1][1], 0, 0, 0);
    acc[1][1] = __builtin_amdgcn_mfma_f32_16x16x32_bf16(a1h, b1l, acc[1][1], 0, 0, 0);
    acc[1][1] = __builtin_amdgcn_mfma_f32_16x16x32_bf16(a1l, b1h, acc[1][1], 0, 0, 0);
    if (kt < 7) writeAB(cur ^ 1);
    __syncthreads();
  }
#pragma unroll
  for (int m = 0; m < 2; m++) {
#pragma unroll
    for (int n = 0; n < 2; n++) {
#pragma unroll
      for (int i = 0; i < 4; i++) {
        int row = row0 + wr * 32 + m * 16 + lk * 4 + i;
        int col = col0 + wcq * 32 + n * 16 + lr;
        float v = acc[m][n][i] + bias512[col];
        if (isW) xc[row * 256 + col] = v;
        else     qb[row * 256 + (col - 256)] = f2bf(v);
      }
    }
  }
}

// ---- offsets: tap-parallel dw-conv + LN + GELU + proj + ref + clip + dtab epilogue ----
__global__ __launch_bounds__(256) void k_offsets(const void* x, const ushortT* qb, const void* w_dw,
                                                 const void* b_dw, const void* ln_g, const void* ln_b,
                                                 const void* w_proj, float* pos, float* dtab) {
  __shared__ float wdw[243 * 33];   // [tap][ch], stride 33
  __shared__ float part[8][33];
  __shared__ float ptile[3];
  int bid = blockIdx.x;             // g*36 + nn
  int g = bid / 36, nn = bid % 36;
  int b = g >> 3, nh = g & 7;
  int tk = nn / 9, hk = (nn / 3) % 3, wk = nn % 3;
  int tid = threadIdx.x;
  int ch = tid & 31, grp = tid >> 5;
  int bf = detect_bf(x);
  for (int i = tid; i < 7776; i += 256) {
    int c = i / 243, tap = i % 243;
    wdw[tap * 33 + c] = ldg_f(w_dw, i, bf);
  }
  __syncthreads();
  float sum = 0.f;
  for (int tap = grp; tap < 243; tap += 8) {
    int dt = tap / 81, rem = tap % 81, dh = rem / 9, dw = rem % 9;
    int t = tk * 2 - 1 + dt, h = hk * 8 - 4 + dh, w = wk * 8 - 4 + dw;
    if (t < 0 || t >= 8 || h < 0 || h >= 24 || w < 0 || w >= 24) continue;
    float qv = bf2f(qb[((b * 8 + t) * 576 + h * 24 + w) * 256 + nh * 32 + ch]);
    sum += qv * wdw[tap * 33 + ch];
  }
  part[grp][ch] = sum;
  __syncthreads();
  if (tid < 32) {
    float v = ldg_f(b_dw, ch, bf);
#pragma unroll
    for (int j = 0; j < 8; j++) v += part[j][ch];
    float s1 = v;
    for (int m = 16; m; m >>= 1) s1 += __shfl_xor(s1, m);
    float mu = s1 * (1.f / 32.f);
    float d = v - mu;
    float s2 = d * d;
    for (int m = 16; m; m >>= 1) s2 += __shfl_xor(s2, m);
    float o = d * rsqrtf(s2 * (1.f / 32.f) + 1e-5f) * ldg_f(ln_g, ch, bf) + ldg_f(ln_b, ch, bf);
    o = 0.5f * o * (1.f + erff(o * 0.70710678118654752f));
    float res[3];
#pragma unroll
    for (int p = 0; p < 3; p++) {
      float t3 = o * ldg_f(w_proj, p * 32 + ch, bf);
      for (int m = 16; m; m >>= 1) t3 += __shfl_xor(t3, m);
      res[p] = t3;
    }
    if (ch == 0) {
      float ref0 = ((tk + 0.5f) / 3.f) * 2.f - 1.f;
      float ref1 = ((hk + 0.5f) / 2.f) * 2.f - 1.f;
      float ref2 = ((wk + 0.5f) / 2.f) * 2.f - 1.f;
      float p0 = fminf(1.f, fmaxf(-1.f, res[0] + ref0));
      float p1 = fminf(1.f, fmaxf(-1.f, res[1] + ref1));
      float p2 = fminf(1.f, fmaxf(-1.f, res[2] + ref2));
      pos[bid * 3 + 0] = p0;
      pos[bid * 3 + 1] = p1;
      pos[bid * 3 + 2] = p2;
      ptile[0] = p0; ptile[1] = p1; ptile[2] = p2;
    }
  }
  __syncthreads();
  // log-CPB displacement tables: [0..7]=d0(t), [8..31]=d1(hh), [32..55]=d2(ww)
  if (tid < 56) {
    float dv;
    if (tid < 8)       dv = ((float)tid        * (2.f / 7.f)  - 1.f - ptile[0]) * 4.f;
    else if (tid < 32) dv = ((float)(tid - 8)  * (2.f / 23.f) - 1.f - ptile[1]) * 4.f;
    else               dv = ((float)(tid - 32) * (2.f / 23.f) - 1.f - ptile[2]) * 4.f;
    dtab[bid * 56 + tid] = logmap(dv);
  }
}

// ---- bias table: 576 blocks (one per (g,nn)); fp32, weights in registers, 18 mm/thread ----
__global__ __launch_bounds__(256) void k_biastab(const void* x, const void* rpe_w1,
                                                 const void* rpe_b1, const void* rpe_w2,
                                                 const float* dtab, float* biastab) {
  int bid = blockIdx.x;             // g*36 + nn
  int tid = threadIdx.x;
  int bf = detect_bf(x);
  __shared__ float dts[56];
  if (tid < 56) dts[tid] = dtab[bid * 56 + tid];
  __syncthreads();
  float d0v[18], d1v[18], d2v[18], acc[18];
#pragma unroll
  for (int i = 0; i < 18; i++) {
    int mm = i * 256 + tid;
    int t = mm / 576, hw = mm % 576, hh = hw / 24, ww = hw % 24;
    d0v[i] = dts[t];
    d1v[i] = dts[8 + hh];
    d2v[i] = dts[32 + ww];
    acc[i] = 0.f;
  }
#pragma unroll
  for (int c = 0; c < 4; c++) {
    float wx[8], wy[8], wz[8], wb[8], w2[8];
#pragma unroll
    for (int j = 0; j < 8; j++) {
      int h = c * 8 + j;
      wx[j] = ldg_f(rpe_w1, h * 3 + 0, bf);
      wy[j] = ldg_f(rpe_w1, h * 3 + 1, bf);
      wz[j] = ldg_f(rpe_w1, h * 3 + 2, bf);
      wb[j] = ldg_f(rpe_b1, h, bf);
      w2[j] = ldg_f(rpe_w2, h, bf);
    }
#pragma unroll
    for (int i = 0; i < 18; i++) {
#pragma unroll
      for (int j = 0; j < 8; j++) {
        float hb = fmaf(d0v[i], wx[j], fmaf(d1v[i], wy[j], fmaf(d2v[i], wz[j], wb[j])));
        acc[i] = fmaf(fmaxf(hb, 0.f), w2[j], acc[i]);
      }
    }
  }
  float* brow = biastab + bid * 4608;
#pragma unroll
  for (int i = 0; i < 18; i++) brow[i * 256 + tid] = acc[i];
}

// ---- fused trilinear sample + k/v 1x1 conv: 288 blocks, pair-split dot ----
__global__ __launch_bounds__(256) void k_svkv(const void* x, const float* xc_rm, const float* pos,
                                              const void* w_k, const void* b_k,
                                              const void* w_v, const void* b_v,
                                              float* k_rm, float* v_rm) {
  int bx = blockIdx.x;
  int row = bx >> 2, quad = bx & 3;
  int sel = quad >> 1, colhalf = quad & 1;
  int b = row / 36, nn = row % 36;
  int tid = threadIdx.x;
  int bf = detect_bf(x);
  __shared__ float a[256];
  {
    int nh = tid >> 5;
    int g = b * 8 + nh;
    float p0 = pos[(g * 36 + nn) * 3 + 0];
    float p1 = pos[(g * 36 + nn) * 3 + 1];
    float p2 = pos[(g * 36 + nn) * 3 + 2];
    float ix = (p0 + 1.f) * 0.5f * 23.f;
    float iy = (p2 + 1.f) * 0.5f * 23.f;
    float iz = (p1 + 1.f) * 0.5f * 7.f;
    float x0f = floorf(ix), y0f = floorf(iy), z0f = floorf(iz);
    float fx = ix - x0f, fy = iy - y0f, fz = iz - z0f;
    int x0 = min(max((int)x0f, 0), 23), x1 = min(x0 + 1, 23);
    int y0 = min(max((int)y0f, 0), 23), y1 = min(y0 + 1, 23);
    int z0 = min(max((int)z0f, 0), 7),  z1 = min(z0 + 1, 7);
#define AT(z, y, x) xc_rm[(((b * 8 + (z)) * 576 + (y) * 24 + (x)) * 256 + tid)]
    a[tid] =
      AT(z0, y0, x0) * (1.f - fz) * (1.f - fy) * (1.f - fx) + AT(z0, y0, x1) * (1.f - fz) * (1.f - fy) * fx +
      AT(z0, y1, x0) * (1.f - fz) * fy * (1.f - fx)         + AT(z0, y1, x1) * (1.f - fz) * fy * fx +
      AT(z1, y0, x0) * fz * (1.f - fy) * (1.f - fx)         + AT(z1, y0, x1) * fz * (1.f - fy) * fx +
      AT(z1, y1, x0) * fz * fy * (1.f - fx)                 + AT(z1, y1, x1) * fz * fy * fx;
#undef AT
  }
  __syncthreads();
  const void* w = sel ? w_v : w_k;
  const void* bb = sel ? b_v : b_k;
  int col = colhalf * 128 + (tid >> 1);
  int half = tid & 1;
  int c0 = half * 128;
  float s = 0.f;
  if (bf) {
    const ushortT* wp = (const ushortT*)w + col * 256 + c0;
#pragma unroll 4
    for (int c = 0; c < 128; c += 8) {
      ushort4 k0 = *(const ushort4*)(wp + c), k1 = *(const ushort4*)(wp + c + 4);
      s += a[c0+c+0]*bf2f(k0.x) + a[c0+c+1]*bf2f(k0.y) + a[c0+c+2]*bf2f(k0.z) + a[c0+c+3]*bf2f(k0.w)
         + a[c0+c+4]*bf2f(k1.x) + a[c0+c+5]*bf2f(k1.y) + a[c0+c+6]*bf2f(k1.z) + a[c0+c+7]*bf2f(k1.w);
    }
  } else {
    const float* wp = (const float*)w + col * 256 + c0;
#pragma unroll 8
    for (int c = 0; c < 128; c += 4) {
      float4 k4 = *(const float4*)(wp + c);
      s += a[c0+c]*k4.x + a[c0+c+1]*k4.y + a[c0+c+2]*k4.z + a[c0+c+3]*k4.w;
    }
  }
  s += __shfl_xor(s, 1);
  if (half == 0) {
    float* outp = sel ? v_rm : k_rm;
    outp[row * 256 + col] = s + ldg_f(bb, col, bf);
  }
}

// ---- attention: QK (bf16 LDS) + bias-table add + softmax + PV; 8-way sub split ----
__global__ __launch_bounds__(256) void k_attn(const void* x, const ushortT* qb,
                                              const float* k_rm, const float* v_rm,
                                              const float* biastab, void* outp) {
  __shared__ ushortT ksb[36][32];
  __shared__ ushortT vsb[36][32];
  int g = blockIdx.y, b = g >> 3, nh = g & 7;
  int tid = threadIdx.x;
  int bf = detect_bf(x);
  for (int e = tid; e < 36 * 32; e += 256) {
    int nn = e >> 5, ch = e & 31;
    ksb[nn][ch] = f2bf(k_rm[(b * 36 + nn) * 256 + nh * 32 + ch]);
    vsb[nn][ch] = f2bf(v_rm[(b * 36 + nn) * 256 + nh * 32 + ch]);
  }
  __syncthreads();

  int sub = tid & 7, chb = sub * 4;
  int mm = blockIdx.x * 32 + (tid >> 3);
  int t = mm / 576, hw = mm % 576;
  float qreg[4];
  {
    ushort4 u = *(const ushort4*)&qb[(b * 4608 + mm) * 256 + nh * 32 + chb];
    qreg[0] = bf2f(u.x); qreg[1] = bf2f(u.y); qreg[2] = bf2f(u.z); qreg[3] = bf2f(u.w);
  }
  const float scale = 0.17677669529663687f;
  const float* brow = biastab + g * 36 * 4608 + mm;
  float p[36];
#pragma unroll
  for (int nn = 0; nn < 36; nn++) {
    ushort4 k4 = *(const ushort4*)&ksb[nn][chb];
    float s = qreg[0] * bf2f(k4.x) + qreg[1] * bf2f(k4.y)
            + qreg[2] * bf2f(k4.z) + qreg[3] * bf2f(k4.w);
    p[nn] = s * scale;
  }
#pragma unroll
  for (int nn = 0; nn < 36; nn++) {
    p[nn] += __shfl_xor(p[nn], 1);
    p[nn] += __shfl_xor(p[nn], 2);
    p[nn] += __shfl_xor(p[nn], 4);
    p[nn] += brow[nn * 4608];
  }
  float mx = -1e30f;
#pragma unroll
  for (int nn = 0; nn < 36; nn++) mx = fmaxf(mx, p[nn]);
  float se = 0.f;
#pragma unroll
  for (int nn = 0; nn < 36; nn++) {
    float e = __expf(p[nn] - mx);
    p[nn] = e;
    se += e;
  }
  float inv = 1.f / se;
  float acc[4] = {};
#pragma unroll
  for (int nn = 0; nn < 36; nn++) {
    float pr = p[nn] * inv;
    ushort4 v4 = *(const ushort4*)&vsb[nn][chb];
    acc[0] += pr * bf2f(v4.x); acc[1] += pr * bf2f(v4.y);
    acc[2] += pr * bf2f(v4.z); acc[3] += pr * bf2f(v4.w);
  }
  int obase = ((b * 8 + t) * 256 + nh * 32 + chb) * 576 + hw;
  if (bf) {
    __hip_bfloat16* o = (__hip_bfloat16*)outp;
#pragma unroll
    for (int j = 0; j < 4; j++) o[obase + j * 576] = __float2bfloat16(acc[j]);
  } else {
    float* o = (float*)outp;
#pragma unroll
    for (int j = 0; j < 4; j++) o[obase + j * 576] = acc[j];
  }
}

extern "C" void kernel_launch(void* const* d_in, const int* in_sizes, int n_in,
                              void* d_out, int out_size, void* d_ws, size_t ws_size,
                              hipStream_t stream) {
  const void* x        = d_in[0];
  const void* w_in     = d_in[1];
  const void* b_in     = d_in[2];
  const void* w_q      = d_in[3];
  const void* b_q      = d_in[4];
  const void* w_off_dw = d_in[5];
  const void* b_off_dw = d_in[6];
  const void* ln_g     = d_in[7];
  const void* ln_b     = d_in[8];
  const void* w_off_pj = d_in[9];
  const void* w_k      = d_in[10];
  const void* b_k      = d_in[11];
  const void* w_v      = d_in[12];
  const void* b_v      = d_in[13];
  const void* rpe_w1   = d_in[14];
  const void* rpe_b1   = d_in[15];
  const void* rpe_w2   = d_in[16];

  float* ws      = (float*)d_ws;
  float* xc      = ws + WS_XC;
  ushortT* qb    = (ushortT*)(ws + WS_QB);
  float* pos     = ws + WS_POS;
  float* krm     = ws + WS_K;
  float* vrm     = ws + WS_V;
  float* wcf     = ws + WS_WC;
  float* b512    = ws + WS_B512;
  float* dtab    = ws + WS_DTAB;
  float* biastab = ws + WS_BIAS;

  k_wc<<<256, 256, 0, stream>>>(x, w_in, b_in, w_q, b_q, wcf, b512);
  k_gemm_mfma<<<1152, 256, 0, stream>>>(x, w_in, wcf, b512, xc, qb);
  k_offsets<<<576, 256, 0, stream>>>(x, qb, w_off_dw, b_off_dw, ln_g, ln_b, w_off_pj, pos, dtab);
  k_biastab<<<576, 256, 0, stream>>>(x, rpe_w1, rpe_b1, rpe_w2, dtab, biastab);
  k_svkv<<<288, 256, 0, stream>>>(x, xc, pos, w_k, b_k, w_v, b_v, krm, vrm);
  k_attn<<<dim3(144, 16), 256, 0, stream>>>(x, qb, krm, vrm, biastab, d_out);
}

// Round 19
// 116.772 us; speedup vs baseline: 1.3707x; 1.1977x over previous
//
#include <hip/hip_runtime.h>
#include <hip/hip_bf16.h>

typedef unsigned short ushortT;
typedef __attribute__((ext_vector_type(8))) short bf16x8;
typedef __attribute__((ext_vector_type(4))) float f32x4;

// workspace float offsets
#define WS_XC   0          // 9216*256 fp32
#define WS_QB   2359296    // 9216*256 bf16
#define WS_POS  3538944    // 16*36*3
#define WS_K    3540736    // 72*256
#define WS_V    3559168    // 72*256
#define WS_WC   3577600    // 256*256 fp32
#define WS_B512 3675904    // 512
#define WS_DTAB 3676416    // 576*56 fp32 log-CPB displacement tables

__device__ __forceinline__ float bf2f(ushortT u) {
  union { unsigned int i; float f; } c; c.i = ((unsigned int)u) << 16; return c.f;
}
__device__ __forceinline__ ushortT f2bf(float f) {
  union { float f; unsigned int i; } c; c.f = f;
  unsigned int lsb = (c.i >> 16) & 1;
  return (ushortT)((c.i + 0x7fff + lsb) >> 16);
}
__device__ __forceinline__ float ldg_f(const void* p, int i, int bf) {
  return bf ? bf2f(((const ushortT*)p)[i]) : ((const float*)p)[i];
}
// uniform dtype sniff of x's first 32 ushorts (fp32 -> wild bf16-exponents in even halves)
__device__ __forceinline__ int detect_bf(const void* x) {
  const ushortT* u = (const ushortT*)x;
  int wild = 0;
#pragma unroll
  for (int i = 0; i < 32; i++) {
    int e = (u[i] >> 7) & 0xFF;
    wild += (e != 0 && (e < 90 || e > 160)) ? 1 : 0;
  }
  return wild <= 4;   // 1 => bf16 inputs
}
__device__ __forceinline__ float logmap(float d) {
  return copysignf(__log2f(fabsf(d) + 1.f) * (1.f / 3.f), d);
}

// -------- k_wc: Wc = Wq*Win (fp32), bias512 = [b_in | Wq*b_in + b_q] --------
__global__ __launch_bounds__(256) void k_wc(const void* x, const void* w_in, const void* b_in,
                                            const void* w_q, const void* b_q,
                                            float* wc, float* bias512) {
  int o = blockIdx.x, tid = threadIdx.x;
  int bf = detect_bf(x);
  __shared__ float wq_s[256];
  __shared__ float red[256];
  wq_s[tid] = ldg_f(w_q, o * 256 + tid, bf);
  __syncthreads();
  float s = 0.f;
#pragma unroll 8
  for (int j = 0; j < 256; j++) s += wq_s[j] * ldg_f(w_in, j * 256 + tid, bf);
  wc[o * 256 + tid] = s;
  red[tid] = wq_s[tid] * ldg_f(b_in, tid, bf);
  __syncthreads();
  for (int m = 128; m; m >>= 1) {
    if (tid < m) red[tid] += red[tid + m];
    __syncthreads();
  }
  if (tid == 0) bias512[256 + o] = red[0] + ldg_f(b_q, o, bf);
  if (o == 0) bias512[tid] = ldg_f(b_in, tid, bf);
}

// -------- fused split-precision MFMA GEMM, double-buffered, truncation split --------
__global__ __launch_bounds__(256) void k_gemm_mfma(const void* x, const void* w_in, const float* wc,
                                                   const float* bias512, float* xc, ushortT* qb) {
  const int bf = detect_bf(x);
  __shared__ ushortT Ah[2][64 * 40], Al[2][64 * 40];
  __shared__ ushortT Bh[2][64 * 40], Bl[2][64 * 40];
  int tid = threadIdx.x;
  int bid = blockIdx.x;
  int colT = bid / 144, rowT = bid % 144;
  int col0 = colT * 64;
  int row0 = rowT * 64;
  int bt = row0 / 576;
  int hw0 = row0 % 576;
  const int isW = (col0 < 256);
  const ushortT* xB = (const ushortT*)x;
  const float*   xF = (const float*)x;
  const ushortT* wB = (const ushortT*)w_in;
  const float*   wF = (const float*)w_in;
  int ar = tid & 63, aoct = tid >> 6;
  int bn = tid >> 2, bko = tid & 3;
  int w = tid >> 6, l = tid & 63;
  int wr = w >> 1, wcq = w & 1;
  int lr = l & 15, lk = l >> 4;
  f32x4 acc[2][2] = {};

  float va[8], vb[8];
  auto loadA = [&](int kt) {
    int kbase = (bt * 256 + kt * 32 + aoct * 8) * 576 + hw0 + ar;
#pragma unroll
    for (int j = 0; j < 8; j++)
      va[j] = bf ? bf2f(xB[kbase + j * 576]) : xF[kbase + j * 576];
  };
  auto loadB = [&](int kt) {
    if (isW) {
      if (bf) {
        const ushortT* pp = wB + (col0 + bn) * 256 + kt * 32 + bko * 8;
#pragma unroll
        for (int j = 0; j < 8; j++) vb[j] = bf2f(pp[j]);
      } else {
        const float* pp = wF + (col0 + bn) * 256 + kt * 32 + bko * 8;
        float4 f0 = *(const float4*)pp;
        float4 f1 = *(const float4*)(pp + 4);
        vb[0] = f0.x; vb[1] = f0.y; vb[2] = f0.z; vb[3] = f0.w;
        vb[4] = f1.x; vb[5] = f1.y; vb[6] = f1.z; vb[7] = f1.w;
      }
    } else {
      const float* pp = wc + (col0 - 256 + bn) * 256 + kt * 32 + bko * 8;
      float4 f0 = *(const float4*)pp;
      float4 f1 = *(const float4*)(pp + 4);
      vb[0] = f0.x; vb[1] = f0.y; vb[2] = f0.z; vb[3] = f0.w;
      vb[4] = f1.x; vb[5] = f1.y; vb[6] = f1.z; vb[7] = f1.w;
    }
  };
  auto writeAB = [&](int buf) {
    unsigned ua[8], ra[8];
#pragma unroll
    for (int j = 0; j < 8; j++) {
      ua[j] = __float_as_uint(va[j]);
      ra[j] = __float_as_uint(va[j] - __uint_as_float(ua[j] & 0xffff0000u));
    }
    int4 ph, pl;
    ph.x = (int)((ua[0] >> 16) | (ua[1] & 0xffff0000u));
    ph.y = (int)((ua[2] >> 16) | (ua[3] & 0xffff0000u));
    ph.z = (int)((ua[4] >> 16) | (ua[5] & 0xffff0000u));
    ph.w = (int)((ua[6] >> 16) | (ua[7] & 0xffff0000u));
    pl.x = (int)((ra[0] >> 16) | (ra[1] & 0xffff0000u));
    pl.y = (int)((ra[2] >> 16) | (ra[3] & 0xffff0000u));
    pl.z = (int)((ra[4] >> 16) | (ra[5] & 0xffff0000u));
    pl.w = (int)((ra[6] >> 16) | (ra[7] & 0xffff0000u));
    *(int4*)&Ah[buf][ar * 40 + aoct * 8] = ph;
    *(int4*)&Al[buf][ar * 40 + aoct * 8] = pl;
#pragma unroll
    for (int j = 0; j < 8; j++) {
      ua[j] = __float_as_uint(vb[j]);
      ra[j] = __float_as_uint(vb[j] - __uint_as_float(ua[j] & 0xffff0000u));
    }
    ph.x = (int)((ua[0] >> 16) | (ua[1] & 0xffff0000u));
    ph.y = (int)((ua[2] >> 16) | (ua[3] & 0xffff0000u));
    ph.z = (int)((ua[4] >> 16) | (ua[5] & 0xffff0000u));
    ph.w = (int)((ua[6] >> 16) | (ua[7] & 0xffff0000u));
    pl.x = (int)((ra[0] >> 16) | (ra[1] & 0xffff0000u));
    pl.y = (int)((ra[2] >> 16) | (ra[3] & 0xffff0000u));
    pl.z = (int)((ra[4] >> 16) | (ra[5] & 0xffff0000u));
    pl.w = (int)((ra[6] >> 16) | (ra[7] & 0xffff0000u));
    *(int4*)&Bh[buf][bn * 40 + bko * 8] = ph;
    *(int4*)&Bl[buf][bn * 40 + bko * 8] = pl;
  };

  loadA(0); loadB(0);
  writeAB(0);
  __syncthreads();
  for (int kt = 0; kt < 8; kt++) {
    int cur = kt & 1;
    if (kt < 7) { loadA(kt + 1); loadB(kt + 1); }
    bf16x8 a0h = *(const bf16x8*)&Ah[cur][(wr * 32 + 0 * 16 + lr) * 40 + lk * 8];
    bf16x8 a1h = *(const bf16x8*)&Ah[cur][(wr * 32 + 1 * 16 + lr) * 40 + lk * 8];
    bf16x8 a0l = *(const bf16x8*)&Al[cur][(wr * 32 + 0 * 16 + lr) * 40 + lk * 8];
    bf16x8 a1l = *(const bf16x8*)&Al[cur][(wr * 32 + 1 * 16 + lr) * 40 + lk * 8];
    bf16x8 b0h = *(const bf16x8*)&Bh[cur][(wcq * 32 + 0 * 16 + lr) * 40 + lk * 8];
    bf16x8 b1h = *(const bf16x8*)&Bh[cur][(wcq * 32 + 1 * 16 + lr) * 40 + lk * 8];
    bf16x8 b0l = *(const bf16x8*)&Bl[cur][(wcq * 32 + 0 * 16 + lr) * 40 + lk * 8];
    bf16x8 b1l = *(const bf16x8*)&Bl[cur][(wcq * 32 + 1 * 16 + lr) * 40 + lk * 8];
    acc[0][0] = __builtin_amdgcn_mfma_f32_16x16x32_bf16(a0h, b0h, acc[0][0], 0, 0, 0);
    acc[0][0] = __builtin_amdgcn_mfma_f32_16x16x32_bf16(a0h, b0l, acc[0][0], 0, 0, 0);
    acc[0][0] = __builtin_amdgcn_mfma_f32_16x16x32_bf16(a0l, b0h, acc[0][0], 0, 0, 0);
    acc[0][1] = __builtin_amdgcn_mfma_f32_16x16x32_bf16(a0h, b1h, acc[0][1], 0, 0, 0);
    acc[0][1] = __builtin_amdgcn_mfma_f32_16x16x32_bf16(a0h, b1l, acc[0][1], 0, 0, 0);
    acc[0][1] = __builtin_amdgcn_mfma_f32_16x16x32_bf16(a0l, b1h, acc[0][1], 0, 0, 0);
    acc[1][0] = __builtin_amdgcn_mfma_f32_16x16x32_bf16(a1h, b0h, acc[1][0], 0, 0, 0);
    acc[1][0] = __builtin_amdgcn_mfma_f32_16x16x32_bf16(a1h, b0l, acc[1][0], 0, 0, 0);
    acc[1][0] = __builtin_amdgcn_mfma_f32_16x16x32_bf16(a1l, b0h, acc[1][0], 0, 0, 0);
    acc[1][1] = __builtin_amdgcn_mfma_f32_16x16x32_bf16(a1h, b1h, acc[1][1], 0, 0, 0);
    acc[1][1] = __builtin_amdgcn_mfma_f32_16x16x32_bf16(a1h, b1l, acc[1][1], 0, 0, 0);
    acc[1][1] = __builtin_amdgcn_mfma_f32_16x16x32_bf16(a1l, b1h, acc[1][1], 0, 0, 0);
    if (kt < 7) writeAB(cur ^ 1);
    __syncthreads();
  }
#pragma unroll
  for (int m = 0; m < 2; m++) {
#pragma unroll
    for (int n = 0; n < 2; n++) {
#pragma unroll
      for (int i = 0; i < 4; i++) {
        int row = row0 + wr * 32 + m * 16 + lk * 4 + i;
        int col = col0 + wcq * 32 + n * 16 + lr;
        float v = acc[m][n][i] + bias512[col];
        if (isW) xc[row * 256 + col] = v;
        else     qb[row * 256 + (col - 256)] = f2bf(v);
      }
    }
  }
}

// ---- offsets: tap-parallel dw-conv + LN + GELU + proj + ref + clip + dtab epilogue ----
__global__ __launch_bounds__(256) void k_offsets(const void* x, const ushortT* qb, const void* w_dw,
                                                 const void* b_dw, const void* ln_g, const void* ln_b,
                                                 const void* w_proj, float* pos, float* dtab) {
  __shared__ float wdw[243 * 33];   // [tap][ch], stride 33
  __shared__ float part[8][33];
  __shared__ float ptile[3];
  int bid = blockIdx.x;             // g*36 + nn
  int g = bid / 36, nn = bid % 36;
  int b = g >> 3, nh = g & 7;
  int tk = nn / 9, hk = (nn / 3) % 3, wk = nn % 3;
  int tid = threadIdx.x;
  int ch = tid & 31, grp = tid >> 5;
  int bf = detect_bf(x);
  for (int i = tid; i < 7776; i += 256) {
    int c = i / 243, tap = i % 243;
    wdw[tap * 33 + c] = ldg_f(w_dw, i, bf);
  }
  __syncthreads();
  float sum = 0.f;
  for (int tap = grp; tap < 243; tap += 8) {
    int dt = tap / 81, rem = tap % 81, dh = rem / 9, dw = rem % 9;
    int t = tk * 2 - 1 + dt, h = hk * 8 - 4 + dh, w = wk * 8 - 4 + dw;
    if (t < 0 || t >= 8 || h < 0 || h >= 24 || w < 0 || w >= 24) continue;
    float qv = bf2f(qb[((b * 8 + t) * 576 + h * 24 + w) * 256 + nh * 32 + ch]);
    sum += qv * wdw[tap * 33 + ch];
  }
  part[grp][ch] = sum;
  __syncthreads();
  if (tid < 32) {
    float v = ldg_f(b_dw, ch, bf);
#pragma unroll
    for (int j = 0; j < 8; j++) v += part[j][ch];
    float s1 = v;
    for (int m = 16; m; m >>= 1) s1 += __shfl_xor(s1, m);
    float mu = s1 * (1.f / 32.f);
    float d = v - mu;
    float s2 = d * d;
    for (int m = 16; m; m >>= 1) s2 += __shfl_xor(s2, m);
    float o = d * rsqrtf(s2 * (1.f / 32.f) + 1e-5f) * ldg_f(ln_g, ch, bf) + ldg_f(ln_b, ch, bf);
    o = 0.5f * o * (1.f + erff(o * 0.70710678118654752f));
    float res[3];
#pragma unroll
    for (int p = 0; p < 3; p++) {
      float t3 = o * ldg_f(w_proj, p * 32 + ch, bf);
      for (int m = 16; m; m >>= 1) t3 += __shfl_xor(t3, m);
      res[p] = t3;
    }
    if (ch == 0) {
      float ref0 = ((tk + 0.5f) / 3.f) * 2.f - 1.f;
      float ref1 = ((hk + 0.5f) / 2.f) * 2.f - 1.f;
      float ref2 = ((wk + 0.5f) / 2.f) * 2.f - 1.f;
      float p0 = fminf(1.f, fmaxf(-1.f, res[0] + ref0));
      float p1 = fminf(1.f, fmaxf(-1.f, res[1] + ref1));
      float p2 = fminf(1.f, fmaxf(-1.f, res[2] + ref2));
      pos[bid * 3 + 0] = p0;
      pos[bid * 3 + 1] = p1;
      pos[bid * 3 + 2] = p2;
      ptile[0] = p0; ptile[1] = p1; ptile[2] = p2;
    }
  }
  __syncthreads();
  // log-CPB displacement tables: [0..7]=d0(t), [8..31]=d1(hh), [32..55]=d2(ww)
  if (tid < 56) {
    float dv;
    if (tid < 8)       dv = ((float)tid        * (2.f / 7.f)  - 1.f - ptile[0]) * 4.f;
    else if (tid < 32) dv = ((float)(tid - 8)  * (2.f / 23.f) - 1.f - ptile[1]) * 4.f;
    else               dv = ((float)(tid - 32) * (2.f / 23.f) - 1.f - ptile[2]) * 4.f;
    dtab[bid * 56 + tid] = logmap(dv);
  }
}

// ---- fused trilinear sample + k/v 1x1 conv: 288 blocks, pair-split dot ----
__global__ __launch_bounds__(256) void k_svkv(const void* x, const float* xc_rm, const float* pos,
                                              const void* w_k, const void* b_k,
                                              const void* w_v, const void* b_v,
                                              float* k_rm, float* v_rm) {
  int bx = blockIdx.x;
  int row = bx >> 2, quad = bx & 3;
  int sel = quad >> 1, colhalf = quad & 1;
  int b = row / 36, nn = row % 36;
  int tid = threadIdx.x;
  int bf = detect_bf(x);
  __shared__ float a[256];
  {
    int nh = tid >> 5;
    int g = b * 8 + nh;
    float p0 = pos[(g * 36 + nn) * 3 + 0];
    float p1 = pos[(g * 36 + nn) * 3 + 1];
    float p2 = pos[(g * 36 + nn) * 3 + 2];
    float ix = (p0 + 1.f) * 0.5f * 23.f;
    float iy = (p2 + 1.f) * 0.5f * 23.f;
    float iz = (p1 + 1.f) * 0.5f * 7.f;
    float x0f = floorf(ix), y0f = floorf(iy), z0f = floorf(iz);
    float fx = ix - x0f, fy = iy - y0f, fz = iz - z0f;
    int x0 = min(max((int)x0f, 0), 23), x1 = min(x0 + 1, 23);
    int y0 = min(max((int)y0f, 0), 23), y1 = min(y0 + 1, 23);
    int z0 = min(max((int)z0f, 0), 7),  z1 = min(z0 + 1, 7);
#define AT(z, y, x) xc_rm[(((b * 8 + (z)) * 576 + (y) * 24 + (x)) * 256 + tid)]
    a[tid] =
      AT(z0, y0, x0) * (1.f - fz) * (1.f - fy) * (1.f - fx) + AT(z0, y0, x1) * (1.f - fz) * (1.f - fy) * fx +
      AT(z0, y1, x0) * (1.f - fz) * fy * (1.f - fx)         + AT(z0, y1, x1) * (1.f - fz) * fy * fx +
      AT(z1, y0, x0) * fz * (1.f - fy) * (1.f - fx)         + AT(z1, y0, x1) * fz * (1.f - fy) * fx +
      AT(z1, y1, x0) * fz * fy * (1.f - fx)                 + AT(z1, y1, x1) * fz * fy * fx;
#undef AT
  }
  __syncthreads();
  const void* w = sel ? w_v : w_k;
  const void* bb = sel ? b_v : b_k;
  int col = colhalf * 128 + (tid >> 1);
  int half = tid & 1;
  int c0 = half * 128;
  float s = 0.f;
  if (bf) {
    const ushortT* wp = (const ushortT*)w + col * 256 + c0;
#pragma unroll 4
    for (int c = 0; c < 128; c += 8) {
      ushort4 k0 = *(const ushort4*)(wp + c), k1 = *(const ushort4*)(wp + c + 4);
      s += a[c0+c+0]*bf2f(k0.x) + a[c0+c+1]*bf2f(k0.y) + a[c0+c+2]*bf2f(k0.z) + a[c0+c+3]*bf2f(k0.w)
         + a[c0+c+4]*bf2f(k1.x) + a[c0+c+5]*bf2f(k1.y) + a[c0+c+6]*bf2f(k1.z) + a[c0+c+7]*bf2f(k1.w);
    }
  } else {
    const float* wp = (const float*)w + col * 256 + c0;
#pragma unroll 8
    for (int c = 0; c < 128; c += 4) {
      float4 k4 = *(const float4*)(wp + c);
      s += a[c0+c]*k4.x + a[c0+c+1]*k4.y + a[c0+c+2]*k4.z + a[c0+c+3]*k4.w;
    }
  }
  s += __shfl_xor(s, 1);
  if (half == 0) {
    float* outp = sel ? v_rm : k_rm;
    outp[row * 256 + col] = s + ldg_f(bb, col, bf);
  }
}

// ---- attention: 8-way sub split; bf16 k/v LDS (b64 reads); transposed dt (b128 reads) ----
__global__ __launch_bounds__(256) void k_attn(const void* x, const ushortT* qb,
                                              const float* k_rm, const float* v_rm,
                                              const float* dtab, const void* rpe_w1,
                                              const void* rpe_b1, const void* rpe_w2, void* outp) {
  __shared__ ushortT ksb[36][32];
  __shared__ ushortT vsb[36][32];
  __shared__ float dtl[56][40];   // [posidx][nn], rows 160B (16B-aligned float4 reads)
  int g = blockIdx.y, b = g >> 3, nh = g & 7;
  int tid = threadIdx.x;
  int bf = detect_bf(x);
  for (int e = tid; e < 36 * 32; e += 256) {
    int nn = e >> 5, ch = e & 31;
    ksb[nn][ch] = f2bf(k_rm[(b * 36 + nn) * 256 + nh * 32 + ch]);
    vsb[nn][ch] = f2bf(v_rm[(b * 36 + nn) * 256 + nh * 32 + ch]);
  }
  for (int e = tid; e < 2016; e += 256) {
    int nn = e / 56, p = e % 56;
    dtl[p][nn] = dtab[g * 2016 + e];
  }
  __syncthreads();

  int sub = tid & 7, chb = sub * 4;
  int mm = blockIdx.x * 32 + (tid >> 3);
  int t = mm / 576, hw = mm % 576, hh = hw / 24, ww = hw % 24;
  float qreg[4];
  {
    ushort4 u = *(const ushort4*)&qb[(b * 4608 + mm) * 256 + nh * 32 + chb];
    qreg[0] = bf2f(u.x); qreg[1] = bf2f(u.y); qreg[2] = bf2f(u.z); qreg[3] = bf2f(u.w);
  }
  float wx[4], wy[4], wz[4], wb_[4], w2[4];
#pragma unroll
  for (int j = 0; j < 4; j++) {
    int h = chb + j;
    wx[j]  = ldg_f(rpe_w1, h * 3 + 0, bf);
    wy[j]  = ldg_f(rpe_w1, h * 3 + 1, bf);
    wz[j]  = ldg_f(rpe_w1, h * 3 + 2, bf);
    wb_[j] = ldg_f(rpe_b1, h, bf);
    w2[j]  = ldg_f(rpe_w2, h, bf);
  }
  const float scale = 0.17677669529663687f;
  float p[36];
#pragma unroll
  for (int nq = 0; nq < 9; nq++) {
    float4 d0q = *(const float4*)&dtl[t][nq * 4];
    float4 d1q = *(const float4*)&dtl[8 + hh][nq * 4];
    float4 d2q = *(const float4*)&dtl[32 + ww][nq * 4];
#pragma unroll
    for (int k = 0; k < 4; k++) {
      int nn = nq * 4 + k;
      ushort4 k4 = *(const ushort4*)&ksb[nn][chb];
      float s = qreg[0] * bf2f(k4.x) + qreg[1] * bf2f(k4.y)
              + qreg[2] * bf2f(k4.z) + qreg[3] * bf2f(k4.w);
      s *= scale;
      float d0 = (k == 0) ? d0q.x : (k == 1) ? d0q.y : (k == 2) ? d0q.z : d0q.w;
      float d1 = (k == 0) ? d1q.x : (k == 1) ? d1q.y : (k == 2) ? d1q.z : d1q.w;
      float d2 = (k == 0) ? d2q.x : (k == 1) ? d2q.y : (k == 2) ? d2q.z : d2q.w;
#pragma unroll
      for (int j = 0; j < 4; j++) {
        float hb = fmaf(d0, wx[j], fmaf(d1, wy[j], fmaf(d2, wz[j], wb_[j])));
        s = fmaf(fmaxf(hb, 0.f), w2[j], s);
      }
      p[nn] = s;
    }
  }
  // combine 8 partials within the lane octet
#pragma unroll
  for (int nn = 0; nn < 36; nn++) {
    p[nn] += __shfl_xor(p[nn], 1);
    p[nn] += __shfl_xor(p[nn], 2);
    p[nn] += __shfl_xor(p[nn], 4);
  }
  float mx = -1e30f;
#pragma unroll
  for (int nn = 0; nn < 36; nn++) mx = fmaxf(mx, p[nn]);
  float se = 0.f;
#pragma unroll
  for (int nn = 0; nn < 36; nn++) {
    float e = __expf(p[nn] - mx);
    p[nn] = e;
    se += e;
  }
  float inv = 1.f / se;
  float acc[4] = {};
#pragma unroll
  for (int nn = 0; nn < 36; nn++) {
    float pr = p[nn] * inv;
    ushort4 v4 = *(const ushort4*)&vsb[nn][chb];
    acc[0] += pr * bf2f(v4.x); acc[1] += pr * bf2f(v4.y);
    acc[2] += pr * bf2f(v4.z); acc[3] += pr * bf2f(v4.w);
  }
  int obase = ((b * 8 + t) * 256 + nh * 32 + chb) * 576 + hw;
  if (bf) {
    __hip_bfloat16* o = (__hip_bfloat16*)outp;
#pragma unroll
    for (int j = 0; j < 4; j++) o[obase + j * 576] = __float2bfloat16(acc[j]);
  } else {
    float* o = (float*)outp;
#pragma unroll
    for (int j = 0; j < 4; j++) o[obase + j * 576] = acc[j];
  }
}

extern "C" void kernel_launch(void* const* d_in, const int* in_sizes, int n_in,
                              void* d_out, int out_size, void* d_ws, size_t ws_size,
                              hipStream_t stream) {
  const void* x        = d_in[0];
  const void* w_in     = d_in[1];
  const void* b_in     = d_in[2];
  const void* w_q      = d_in[3];
  const void* b_q      = d_in[4];
  const void* w_off_dw = d_in[5];
  const void* b_off_dw = d_in[6];
  const void* ln_g     = d_in[7];
  const void* ln_b     = d_in[8];
  const void* w_off_pj = d_in[9];
  const void* w_k      = d_in[10];
  const void* b_k      = d_in[11];
  const void* w_v      = d_in[12];
  const void* b_v      = d_in[13];
  const void* rpe_w1   = d_in[14];
  const void* rpe_b1   = d_in[15];
  const void* rpe_w2   = d_in[16];

  float* ws    = (float*)d_ws;
  float* xc    = ws + WS_XC;
  ushortT* qb  = (ushortT*)(ws + WS_QB);
  float* pos   = ws + WS_POS;
  float* krm   = ws + WS_K;
  float* vrm   = ws + WS_V;
  float* wcf   = ws + WS_WC;
  float* b512  = ws + WS_B512;
  float* dtab  = ws + WS_DTAB;

  k_wc<<<256, 256, 0, stream>>>(x, w_in, b_in, w_q, b_q, wcf, b512);
  k_gemm_mfma<<<1152, 256, 0, stream>>>(x, w_in, wcf, b512, xc, qb);
  k_offsets<<<576, 256, 0, stream>>>(x, qb, w_off_dw, b_off_dw, ln_g, ln_b, w_off_pj, pos, dtab);
  k_svkv<<<288, 256, 0, stream>>>(x, xc, pos, w_k, b_k, w_v, b_v, krm, vrm);
  k_attn<<<dim3(144, 16), 256, 0, stream>>>(x, qb, krm, vrm, dtab, rpe_w1, rpe_b1, rpe_w2, d_out);
}

// Round 20
// 113.834 us; speedup vs baseline: 1.4061x; 1.0258x over previous
//
#include <hip/hip_runtime.h>
#include <hip/hip_bf16.h>

typedef unsigned short ushortT;
typedef __attribute__((ext_vector_type(8))) short bf16x8;
typedef __attribute__((ext_vector_type(4))) float f32x4;

// workspace float offsets
#define WS_XC   0          // 9216*256 fp32
#define WS_QB   2359296    // 9216*256 bf16
#define WS_POS  3538944    // 16*36*3
#define WS_K    3540736    // 72*256
#define WS_V    3559168    // 72*256
#define WS_WC   3577600    // 256*256 fp32
#define WS_B512 3675904    // 512
#define WS_DTAB 3676416    // 576*56 fp32 log-CPB displacement tables

__device__ __forceinline__ float bf2f(ushortT u) {
  union { unsigned int i; float f; } c; c.i = ((unsigned int)u) << 16; return c.f;
}
__device__ __forceinline__ ushortT f2bf(float f) {
  union { float f; unsigned int i; } c; c.f = f;
  unsigned int lsb = (c.i >> 16) & 1;
  return (ushortT)((c.i + 0x7fff + lsb) >> 16);
}
__device__ __forceinline__ float ldg_f(const void* p, int i, int bf) {
  return bf ? bf2f(((const ushortT*)p)[i]) : ((const float*)p)[i];
}
// uniform dtype sniff of x's first 32 ushorts (fp32 -> wild bf16-exponents in even halves)
__device__ __forceinline__ int detect_bf(const void* x) {
  const ushortT* u = (const ushortT*)x;
  int wild = 0;
#pragma unroll
  for (int i = 0; i < 32; i++) {
    int e = (u[i] >> 7) & 0xFF;
    wild += (e != 0 && (e < 90 || e > 160)) ? 1 : 0;
  }
  return wild <= 4;   // 1 => bf16 inputs
}
__device__ __forceinline__ float logmap(float d) {
  return copysignf(__log2f(fabsf(d) + 1.f) * (1.f / 3.f), d);
}

// -------- k_wc: Wc = Wq*Win (fp32), bias512 = [b_in | Wq*b_in + b_q] --------
__global__ __launch_bounds__(256) void k_wc(const void* x, const void* w_in, const void* b_in,
                                            const void* w_q, const void* b_q,
                                            float* wc, float* bias512) {
  int o = blockIdx.x, tid = threadIdx.x;
  int bf = detect_bf(x);
  __shared__ float wq_s[256];
  __shared__ float red[256];
  wq_s[tid] = ldg_f(w_q, o * 256 + tid, bf);
  __syncthreads();
  float s = 0.f;
#pragma unroll 8
  for (int j = 0; j < 256; j++) s += wq_s[j] * ldg_f(w_in, j * 256 + tid, bf);
  wc[o * 256 + tid] = s;
  red[tid] = wq_s[tid] * ldg_f(b_in, tid, bf);
  __syncthreads();
  for (int m = 128; m; m >>= 1) {
    if (tid < m) red[tid] += red[tid + m];
    __syncthreads();
  }
  if (tid == 0) bias512[256 + o] = red[0] + ldg_f(b_q, o, bf);
  if (o == 0) bias512[tid] = ldg_f(b_in, tid, bf);
}

// -------- fused split-precision MFMA GEMM, double-buffered, truncation split --------
__global__ __launch_bounds__(256) void k_gemm_mfma(const void* x, const void* w_in, const float* wc,
                                                   const float* bias512, float* xc, ushortT* qb) {
  const int bf = detect_bf(x);
  __shared__ ushortT Ah[2][64 * 40], Al[2][64 * 40];
  __shared__ ushortT Bh[2][64 * 40], Bl[2][64 * 40];
  int tid = threadIdx.x;
  int bid = blockIdx.x;
  int colT = bid / 144, rowT = bid % 144;
  int col0 = colT * 64;
  int row0 = rowT * 64;
  int bt = row0 / 576;
  int hw0 = row0 % 576;
  const int isW = (col0 < 256);
  const ushortT* xB = (const ushortT*)x;
  const float*   xF = (const float*)x;
  const ushortT* wB = (const ushortT*)w_in;
  const float*   wF = (const float*)w_in;
  int ar = tid & 63, aoct = tid >> 6;
  int bn = tid >> 2, bko = tid & 3;
  int w = tid >> 6, l = tid & 63;
  int wr = w >> 1, wcq = w & 1;
  int lr = l & 15, lk = l >> 4;
  f32x4 acc[2][2] = {};

  float va[8], vb[8];
  auto loadA = [&](int kt) {
    int kbase = (bt * 256 + kt * 32 + aoct * 8) * 576 + hw0 + ar;
#pragma unroll
    for (int j = 0; j < 8; j++)
      va[j] = bf ? bf2f(xB[kbase + j * 576]) : xF[kbase + j * 576];
  };
  auto loadB = [&](int kt) {
    if (isW) {
      if (bf) {
        const ushortT* pp = wB + (col0 + bn) * 256 + kt * 32 + bko * 8;
#pragma unroll
        for (int j = 0; j < 8; j++) vb[j] = bf2f(pp[j]);
      } else {
        const float* pp = wF + (col0 + bn) * 256 + kt * 32 + bko * 8;
        float4 f0 = *(const float4*)pp;
        float4 f1 = *(const float4*)(pp + 4);
        vb[0] = f0.x; vb[1] = f0.y; vb[2] = f0.z; vb[3] = f0.w;
        vb[4] = f1.x; vb[5] = f1.y; vb[6] = f1.z; vb[7] = f1.w;
      }
    } else {
      const float* pp = wc + (col0 - 256 + bn) * 256 + kt * 32 + bko * 8;
      float4 f0 = *(const float4*)pp;
      float4 f1 = *(const float4*)(pp + 4);
      vb[0] = f0.x; vb[1] = f0.y; vb[2] = f0.z; vb[3] = f0.w;
      vb[4] = f1.x; vb[5] = f1.y; vb[6] = f1.z; vb[7] = f1.w;
    }
  };
  auto writeAB = [&](int buf) {
    unsigned ua[8], ra[8];
#pragma unroll
    for (int j = 0; j < 8; j++) {
      ua[j] = __float_as_uint(va[j]);
      ra[j] = __float_as_uint(va[j] - __uint_as_float(ua[j] & 0xffff0000u));
    }
    int4 ph, pl;
    ph.x = (int)((ua[0] >> 16) | (ua[1] & 0xffff0000u));
    ph.y = (int)((ua[2] >> 16) | (ua[3] & 0xffff0000u));
    ph.z = (int)((ua[4] >> 16) | (ua[5] & 0xffff0000u));
    ph.w = (int)((ua[6] >> 16) | (ua[7] & 0xffff0000u));
    pl.x = (int)((ra[0] >> 16) | (ra[1] & 0xffff0000u));
    pl.y = (int)((ra[2] >> 16) | (ra[3] & 0xffff0000u));
    pl.z = (int)((ra[4] >> 16) | (ra[5] & 0xffff0000u));
    pl.w = (int)((ra[6] >> 16) | (ra[7] & 0xffff0000u));
    *(int4*)&Ah[buf][ar * 40 + aoct * 8] = ph;
    *(int4*)&Al[buf][ar * 40 + aoct * 8] = pl;
#pragma unroll
    for (int j = 0; j < 8; j++) {
      ua[j] = __float_as_uint(vb[j]);
      ra[j] = __float_as_uint(vb[j] - __uint_as_float(ua[j] & 0xffff0000u));
    }
    ph.x = (int)((ua[0] >> 16) | (ua[1] & 0xffff0000u));
    ph.y = (int)((ua[2] >> 16) | (ua[3] & 0xffff0000u));
    ph.z = (int)((ua[4] >> 16) | (ua[5] & 0xffff0000u));
    ph.w = (int)((ua[6] >> 16) | (ua[7] & 0xffff0000u));
    pl.x = (int)((ra[0] >> 16) | (ra[1] & 0xffff0000u));
    pl.y = (int)((ra[2] >> 16) | (ra[3] & 0xffff0000u));
    pl.z = (int)((ra[4] >> 16) | (ra[5] & 0xffff0000u));
    pl.w = (int)((ra[6] >> 16) | (ra[7] & 0xffff0000u));
    *(int4*)&Bh[buf][bn * 40 + bko * 8] = ph;
    *(int4*)&Bl[buf][bn * 40 + bko * 8] = pl;
  };

  loadA(0); loadB(0);
  writeAB(0);
  __syncthreads();
  for (int kt = 0; kt < 8; kt++) {
    int cur = kt & 1;
    if (kt < 7) { loadA(kt + 1); loadB(kt + 1); }
    bf16x8 a0h = *(const bf16x8*)&Ah[cur][(wr * 32 + 0 * 16 + lr) * 40 + lk * 8];
    bf16x8 a1h = *(const bf16x8*)&Ah[cur][(wr * 32 + 1 * 16 + lr) * 40 + lk * 8];
    bf16x8 a0l = *(const bf16x8*)&Al[cur][(wr * 32 + 0 * 16 + lr) * 40 + lk * 8];
    bf16x8 a1l = *(const bf16x8*)&Al[cur][(wr * 32 + 1 * 16 + lr) * 40 + lk * 8];
    bf16x8 b0h = *(const bf16x8*)&Bh[cur][(wcq * 32 + 0 * 16 + lr) * 40 + lk * 8];
    bf16x8 b1h = *(const bf16x8*)&Bh[cur][(wcq * 32 + 1 * 16 + lr) * 40 + lk * 8];
    bf16x8 b0l = *(const bf16x8*)&Bl[cur][(wcq * 32 + 0 * 16 + lr) * 40 + lk * 8];
    bf16x8 b1l = *(const bf16x8*)&Bl[cur][(wcq * 32 + 1 * 16 + lr) * 40 + lk * 8];
    acc[0][0] = __builtin_amdgcn_mfma_f32_16x16x32_bf16(a0h, b0h, acc[0][0], 0, 0, 0);
    acc[0][0] = __builtin_amdgcn_mfma_f32_16x16x32_bf16(a0h, b0l, acc[0][0], 0, 0, 0);
    acc[0][0] = __builtin_amdgcn_mfma_f32_16x16x32_bf16(a0l, b0h, acc[0][0], 0, 0, 0);
    acc[0][1] = __builtin_amdgcn_mfma_f32_16x16x32_bf16(a0h, b1h, acc[0][1], 0, 0, 0);
    acc[0][1] = __builtin_amdgcn_mfma_f32_16x16x32_bf16(a0h, b1l, acc[0][1], 0, 0, 0);
    acc[0][1] = __builtin_amdgcn_mfma_f32_16x16x32_bf16(a0l, b1h, acc[0][1], 0, 0, 0);
    acc[1][0] = __builtin_amdgcn_mfma_f32_16x16x32_bf16(a1h, b0h, acc[1][0], 0, 0, 0);
    acc[1][0] = __builtin_amdgcn_mfma_f32_16x16x32_bf16(a1h, b0l, acc[1][0], 0, 0, 0);
    acc[1][0] = __builtin_amdgcn_mfma_f32_16x16x32_bf16(a1l, b0h, acc[1][0], 0, 0, 0);
    acc[1][1] = __builtin_amdgcn_mfma_f32_16x16x32_bf16(a1h, b1h, acc[1][1], 0, 0, 0);
    acc[1][1] = __builtin_amdgcn_mfma_f32_16x16x32_bf16(a1h, b1l, acc[1][1], 0, 0, 0);
    acc[1][1] = __builtin_amdgcn_mfma_f32_16x16x32_bf16(a1l, b1h, acc[1][1], 0, 0, 0);
    if (kt < 7) writeAB(cur ^ 1);
    __syncthreads();
  }
#pragma unroll
  for (int m = 0; m < 2; m++) {
#pragma unroll
    for (int n = 0; n < 2; n++) {
#pragma unroll
      for (int i = 0; i < 4; i++) {
        int row = row0 + wr * 32 + m * 16 + lk * 4 + i;
        int col = col0 + wcq * 32 + n * 16 + lr;
        float v = acc[m][n][i] + bias512[col];
        if (isW) xc[row * 256 + col] = v;
        else     qb[row * 256 + (col - 256)] = f2bf(v);
      }
    }
  }
}

// ---- offsets: tap-parallel dw-conv + LN + GELU + proj + ref + clip + dtab epilogue ----
__global__ __launch_bounds__(256) void k_offsets(const void* x, const ushortT* qb, const void* w_dw,
                                                 const void* b_dw, const void* ln_g, const void* ln_b,
                                                 const void* w_proj, float* pos, float* dtab) {
  __shared__ float wdw[243 * 33];   // [tap][ch], stride 33
  __shared__ float part[8][33];
  __shared__ float ptile[3];
  int bid = blockIdx.x;             // g*36 + nn
  int g = bid / 36, nn = bid % 36;
  int b = g >> 3, nh = g & 7;
  int tk = nn / 9, hk = (nn / 3) % 3, wk = nn % 3;
  int tid = threadIdx.x;
  int ch = tid & 31, grp = tid >> 5;
  int bf = detect_bf(x);
  for (int i = tid; i < 7776; i += 256) {
    int c = i / 243, tap = i % 243;
    wdw[tap * 33 + c] = ldg_f(w_dw, i, bf);
  }
  __syncthreads();
  float sum = 0.f;
  for (int tap = grp; tap < 243; tap += 8) {
    int dt = tap / 81, rem = tap % 81, dh = rem / 9, dw = rem % 9;
    int t = tk * 2 - 1 + dt, h = hk * 8 - 4 + dh, w = wk * 8 - 4 + dw;
    if (t < 0 || t >= 8 || h < 0 || h >= 24 || w < 0 || w >= 24) continue;
    float qv = bf2f(qb[((b * 8 + t) * 576 + h * 24 + w) * 256 + nh * 32 + ch]);
    sum += qv * wdw[tap * 33 + ch];
  }
  part[grp][ch] = sum;
  __syncthreads();
  if (tid < 32) {
    float v = ldg_f(b_dw, ch, bf);
#pragma unroll
    for (int j = 0; j < 8; j++) v += part[j][ch];
    float s1 = v;
    for (int m = 16; m; m >>= 1) s1 += __shfl_xor(s1, m);
    float mu = s1 * (1.f / 32.f);
    float d = v - mu;
    float s2 = d * d;
    for (int m = 16; m; m >>= 1) s2 += __shfl_xor(s2, m);
    float o = d * rsqrtf(s2 * (1.f / 32.f) + 1e-5f) * ldg_f(ln_g, ch, bf) + ldg_f(ln_b, ch, bf);
    o = 0.5f * o * (1.f + erff(o * 0.70710678118654752f));
    float res[3];
#pragma unroll
    for (int p = 0; p < 3; p++) {
      float t3 = o * ldg_f(w_proj, p * 32 + ch, bf);
      for (int m = 16; m; m >>= 1) t3 += __shfl_xor(t3, m);
      res[p] = t3;
    }
    if (ch == 0) {
      float ref0 = ((tk + 0.5f) / 3.f) * 2.f - 1.f;
      float ref1 = ((hk + 0.5f) / 2.f) * 2.f - 1.f;
      float ref2 = ((wk + 0.5f) / 2.f) * 2.f - 1.f;
      float p0 = fminf(1.f, fmaxf(-1.f, res[0] + ref0));
      float p1 = fminf(1.f, fmaxf(-1.f, res[1] + ref1));
      float p2 = fminf(1.f, fmaxf(-1.f, res[2] + ref2));
      pos[bid * 3 + 0] = p0;
      pos[bid * 3 + 1] = p1;
      pos[bid * 3 + 2] = p2;
      ptile[0] = p0; ptile[1] = p1; ptile[2] = p2;
    }
  }
  __syncthreads();
  // log-CPB displacement tables: [0..7]=d0(t), [8..31]=d1(hh), [32..55]=d2(ww)
  if (tid < 56) {
    float dv;
    if (tid < 8)       dv = ((float)tid        * (2.f / 7.f)  - 1.f - ptile[0]) * 4.f;
    else if (tid < 32) dv = ((float)(tid - 8)  * (2.f / 23.f) - 1.f - ptile[1]) * 4.f;
    else               dv = ((float)(tid - 32) * (2.f / 23.f) - 1.f - ptile[2]) * 4.f;
    dtab[bid * 56 + tid] = logmap(dv);
  }
}

// ---- fused trilinear sample + k/v 1x1 conv: 576 blocks, quad-split dot ----
// bx = row*8 + oct; sel = oct>>2, colq = oct&3; col = colq*64 + (tid>>2);
// lane quad (tid&3) each sums 64 ch, combined by shfl_xor(1),(2).
__global__ __launch_bounds__(256) void k_svkv(const void* x, const float* xc_rm, const float* pos,
                                              const void* w_k, const void* b_k,
                                              const void* w_v, const void* b_v,
                                              float* k_rm, float* v_rm) {
  int bx = blockIdx.x;
  int row = bx >> 3, oct = bx & 7;
  int sel = oct >> 2, colq = oct & 3;
  int b = row / 36, nn = row % 36;
  int tid = threadIdx.x;
  int bf = detect_bf(x);
  __shared__ float a[256];
  {
    int nh = tid >> 5;
    int g = b * 8 + nh;
    float p0 = pos[(g * 36 + nn) * 3 + 0];
    float p1 = pos[(g * 36 + nn) * 3 + 1];
    float p2 = pos[(g * 36 + nn) * 3 + 2];
    float ix = (p0 + 1.f) * 0.5f * 23.f;
    float iy = (p2 + 1.f) * 0.5f * 23.f;
    float iz = (p1 + 1.f) * 0.5f * 7.f;
    float x0f = floorf(ix), y0f = floorf(iy), z0f = floorf(iz);
    float fx = ix - x0f, fy = iy - y0f, fz = iz - z0f;
    int x0 = min(max((int)x0f, 0), 23), x1 = min(x0 + 1, 23);
    int y0 = min(max((int)y0f, 0), 23), y1 = min(y0 + 1, 23);
    int z0 = min(max((int)z0f, 0), 7),  z1 = min(z0 + 1, 7);
#define AT(z, y, x) xc_rm[(((b * 8 + (z)) * 576 + (y) * 24 + (x)) * 256 + tid)]
    a[tid] =
      AT(z0, y0, x0) * (1.f - fz) * (1.f - fy) * (1.f - fx) + AT(z0, y0, x1) * (1.f - fz) * (1.f - fy) * fx +
      AT(z0, y1, x0) * (1.f - fz) * fy * (1.f - fx)         + AT(z0, y1, x1) * (1.f - fz) * fy * fx +
      AT(z1, y0, x0) * fz * (1.f - fy) * (1.f - fx)         + AT(z1, y0, x1) * fz * (1.f - fy) * fx +
      AT(z1, y1, x0) * fz * fy * (1.f - fx)                 + AT(z1, y1, x1) * fz * fy * fx;
#undef AT
  }
  __syncthreads();
  const void* w = sel ? w_v : w_k;
  const void* bb = sel ? b_v : b_k;
  int col = colq * 64 + (tid >> 2);
  int qlane = tid & 3;
  int c0 = qlane * 64;
  float s = 0.f;
  if (bf) {
    const ushortT* wp = (const ushortT*)w + col * 256 + c0;
#pragma unroll 4
    for (int c = 0; c < 64; c += 8) {
      ushort4 k0 = *(const ushort4*)(wp + c), k1 = *(const ushort4*)(wp + c + 4);
      s += a[c0+c+0]*bf2f(k0.x) + a[c0+c+1]*bf2f(k0.y) + a[c0+c+2]*bf2f(k0.z) + a[c0+c+3]*bf2f(k0.w)
         + a[c0+c+4]*bf2f(k1.x) + a[c0+c+5]*bf2f(k1.y) + a[c0+c+6]*bf2f(k1.z) + a[c0+c+7]*bf2f(k1.w);
    }
  } else {
    const float* wp = (const float*)w + col * 256 + c0;
#pragma unroll 8
    for (int c = 0; c < 64; c += 4) {
      float4 k4 = *(const float4*)(wp + c);
      s += a[c0+c]*k4.x + a[c0+c+1]*k4.y + a[c0+c+2]*k4.z + a[c0+c+3]*k4.w;
    }
  }
  s += __shfl_xor(s, 1);
  s += __shfl_xor(s, 2);
  if (qlane == 0) {
    float* outp = sel ? v_rm : k_rm;
    outp[row * 256 + col] = s + ldg_f(bb, col, bf);
  }
}

// ---- attention: 8-way sub split; fp32 k/v LDS (b128 reads); transposed dt (b128 reads) ----
__global__ __launch_bounds__(256) void k_attn(const void* x, const ushortT* qb,
                                              const float* k_rm, const float* v_rm,
                                              const float* dtab, const void* rpe_w1,
                                              const void* rpe_b1, const void* rpe_w2, void* outp) {
  __shared__ float ks[36][32];
  __shared__ float vs[36][32];
  __shared__ float dtl[56][40];   // [posidx][nn], rows 160B (16B-aligned float4 reads)
  int g = blockIdx.y, b = g >> 3, nh = g & 7;
  int tid = threadIdx.x;
  int bf = detect_bf(x);
  for (int e = tid; e < 36 * 32; e += 256) {
    int nn = e >> 5, ch = e & 31;
    ks[nn][ch] = k_rm[(b * 36 + nn) * 256 + nh * 32 + ch];
    vs[nn][ch] = v_rm[(b * 36 + nn) * 256 + nh * 32 + ch];
  }
  for (int e = tid; e < 2016; e += 256) {
    int nn = e / 56, p = e % 56;
    dtl[p][nn] = dtab[g * 2016 + e];
  }
  __syncthreads();

  int sub = tid & 7, chb = sub * 4;
  int mm = blockIdx.x * 32 + (tid >> 3);
  int t = mm / 576, hw = mm % 576, hh = hw / 24, ww = hw % 24;
  float qreg[4];
  {
    ushort4 u = *(const ushort4*)&qb[(b * 4608 + mm) * 256 + nh * 32 + chb];
    qreg[0] = bf2f(u.x); qreg[1] = bf2f(u.y); qreg[2] = bf2f(u.z); qreg[3] = bf2f(u.w);
  }
  float wx[4], wy[4], wz[4], wb_[4], w2[4];
#pragma unroll
  for (int j = 0; j < 4; j++) {
    int h = chb + j;
    wx[j]  = ldg_f(rpe_w1, h * 3 + 0, bf);
    wy[j]  = ldg_f(rpe_w1, h * 3 + 1, bf);
    wz[j]  = ldg_f(rpe_w1, h * 3 + 2, bf);
    wb_[j] = ldg_f(rpe_b1, h, bf);
    w2[j]  = ldg_f(rpe_w2, h, bf);
  }
  const float scale = 0.17677669529663687f;
  float p[36];
#pragma unroll
  for (int nq = 0; nq < 9; nq++) {
    float4 d0q = *(const float4*)&dtl[t][nq * 4];
    float4 d1q = *(const float4*)&dtl[8 + hh][nq * 4];
    float4 d2q = *(const float4*)&dtl[32 + ww][nq * 4];
#pragma unroll
    for (int k = 0; k < 4; k++) {
      int nn = nq * 4 + k;
      float4 k4 = *(const float4*)&ks[nn][chb];
      float s = qreg[0] * k4.x + qreg[1] * k4.y + qreg[2] * k4.z + qreg[3] * k4.w;
      s *= scale;
      float d0 = (k == 0) ? d0q.x : (k == 1) ? d0q.y : (k == 2) ? d0q.z : d0q.w;
      float d1 = (k == 0) ? d1q.x : (k == 1) ? d1q.y : (k == 2) ? d1q.z : d1q.w;
      float d2 = (k == 0) ? d2q.x : (k == 1) ? d2q.y : (k == 2) ? d2q.z : d2q.w;
#pragma unroll
      for (int j = 0; j < 4; j++) {
        float hb = fmaf(d0, wx[j], fmaf(d1, wy[j], fmaf(d2, wz[j], wb_[j])));
        s = fmaf(fmaxf(hb, 0.f), w2[j], s);
      }
      p[nn] = s;
    }
  }
  // combine 8 partials within the lane octet
#pragma unroll
  for (int nn = 0; nn < 36; nn++) {
    p[nn] += __shfl_xor(p[nn], 1);
    p[nn] += __shfl_xor(p[nn], 2);
    p[nn] += __shfl_xor(p[nn], 4);
  }
  float mx = -1e30f;
#pragma unroll
  for (int nn = 0; nn < 36; nn++) mx = fmaxf(mx, p[nn]);
  float se = 0.f;
#pragma unroll
  for (int nn = 0; nn < 36; nn++) {
    float e = __expf(p[nn] - mx);
    p[nn] = e;
    se += e;
  }
  float inv = 1.f / se;
  float acc[4] = {};
#pragma unroll
  for (int nn = 0; nn < 36; nn++) {
    float pr = p[nn] * inv;
    float4 v4 = *(const float4*)&vs[nn][chb];
    acc[0] += pr * v4.x; acc[1] += pr * v4.y;
    acc[2] += pr * v4.z; acc[3] += pr * v4.w;
  }
  int obase = ((b * 8 + t) * 256 + nh * 32 + chb) * 576 + hw;
  if (bf) {
    __hip_bfloat16* o = (__hip_bfloat16*)outp;
#pragma unroll
    for (int j = 0; j < 4; j++) o[obase + j * 576] = __float2bfloat16(acc[j]);
  } else {
    float* o = (float*)outp;
#pragma unroll
    for (int j = 0; j < 4; j++) o[obase + j * 576] = acc[j];
  }
}

extern "C" void kernel_launch(void* const* d_in, const int* in_sizes, int n_in,
                              void* d_out, int out_size, void* d_ws, size_t ws_size,
                              hipStream_t stream) {
  const void* x        = d_in[0];
  const void* w_in     = d_in[1];
  const void* b_in     = d_in[2];
  const void* w_q      = d_in[3];
  const void* b_q      = d_in[4];
  const void* w_off_dw = d_in[5];
  const void* b_off_dw = d_in[6];
  const void* ln_g     = d_in[7];
  const void* ln_b     = d_in[8];
  const void* w_off_pj = d_in[9];
  const void* w_k      = d_in[10];
  const void* b_k      = d_in[11];
  const void* w_v      = d_in[12];
  const void* b_v      = d_in[13];
  const void* rpe_w1   = d_in[14];
  const void* rpe_b1   = d_in[15];
  const void* rpe_w2   = d_in[16];

  float* ws    = (float*)d_ws;
  float* xc    = ws + WS_XC;
  ushortT* qb  = (ushortT*)(ws + WS_QB);
  float* pos   = ws + WS_POS;
  float* krm   = ws + WS_K;
  float* vrm   = ws + WS_V;
  float* wcf   = ws + WS_WC;
  float* b512  = ws + WS_B512;
  float* dtab  = ws + WS_DTAB;

  k_wc<<<256, 256, 0, stream>>>(x, w_in, b_in, w_q, b_q, wcf, b512);
  k_gemm_mfma<<<1152, 256, 0, stream>>>(x, w_in, wcf, b512, xc, qb);
  k_offsets<<<576, 256, 0, stream>>>(x, qb, w_off_dw, b_off_dw, ln_g, ln_b, w_off_pj, pos, dtab);
  k_svkv<<<576, 256, 0, stream>>>(x, xc, pos, w_k, b_k, w_v, b_v, krm, vrm);
  k_attn<<<dim3(144, 16), 256, 0, stream>>>(x, qb, krm, vrm, dtab, rpe_w1, rpe_b1, rpe_w2, d_out);
}